// Round 1
// baseline (555.855 us; speedup 1.0000x reference)
//
#include <hip/hip_runtime.h>
#include <math.h>

// ---------------------------------------------------------------------------
// 2-layer GCN: out = ReLU(N(x@W1)+b1) -> N(h@W2)+b2, N(.) = D^-1/2 (A+I) D^-1/2
// Strategy: fold dinv[src] into GEMM epilogue, dinv[dst] into agg epilogue.
// CSR by dst (counting sort) -> one wave per node register-accumulated gather.
// ---------------------------------------------------------------------------

__global__ __launch_bounds__(256) void k_count(const int* __restrict__ dst, int E,
                                               int* __restrict__ deg) {
  int e = blockIdx.x * 256 + threadIdx.x;
  if (e < E) atomicAdd(&deg[dst[e]], 1);
}

__global__ __launch_bounds__(1024) void k_scanA(const int* __restrict__ deg, int N,
                                                int* __restrict__ offs,
                                                int* __restrict__ bsum) {
  __shared__ int sd[1024];
  int tid = threadIdx.x;
  int i = blockIdx.x * 1024 + tid;
  int v = (i < N) ? deg[i] : 0;
  sd[tid] = v;
  __syncthreads();
  for (int off = 1; off < 1024; off <<= 1) {
    int t = (tid >= off) ? sd[tid - off] : 0;
    __syncthreads();
    sd[tid] += t;
    __syncthreads();
  }
  if (i < N) offs[i] = sd[tid] - v;  // block-local exclusive
  if (tid == 1023) bsum[blockIdx.x] = sd[1023];
}

__global__ void k_scanB(int* bsum, int nb) {  // 1 block x 64, nb <= 64
  int lane = threadIdx.x;
  int v = (lane < nb) ? bsum[lane] : 0;
  int orig = v;
  for (int off = 1; off < 64; off <<= 1) {
    int t = __shfl_up(v, off, 64);
    if (lane >= off) v += t;
  }
  if (lane < nb) bsum[lane] = v - orig;  // exclusive
}

__global__ __launch_bounds__(256) void k_scanC(const int* __restrict__ deg,
                                               const int* __restrict__ bsum, int N,
                                               int* __restrict__ offs,
                                               int* __restrict__ cursor,
                                               float* __restrict__ dinv) {
  int i = blockIdx.x * 256 + threadIdx.x;
  if (i < N) {
    int o = offs[i] + bsum[i >> 10];
    offs[i] = o;
    cursor[i] = o;
    dinv[i] = rsqrtf((float)(deg[i] + 1));  // +1 = self loop
  }
}

__global__ __launch_bounds__(256) void k_fill(const int* __restrict__ src,
                                              const int* __restrict__ dstv, int E,
                                              int* __restrict__ cursor,
                                              int* __restrict__ csr) {
  int e = blockIdx.x * 256 + threadIdx.x;
  if (e < E) {
    int p = atomicAdd(&cursor[dstv[e]], 1);
    csr[p] = src[e];
  }
}

// O[r][c] = (sum_k X[r][k] W[k][c]) * dinv[r].  64x64 tile, BK=64, 4x4 micro.
__global__ __launch_bounds__(256) void k_gemm_scaled(
    const float* __restrict__ X, const float* __restrict__ W,
    const float* __restrict__ dinv, float* __restrict__ O,
    int M, int K, int NC) {
  __shared__ float xT[64][68];  // [k][row], stride 68 keeps 16B align, spreads banks
  __shared__ float ws[64][64];  // [k][col]
  const int tid = threadIdx.x;
  const int tx = tid & 15;
  const int ty = tid >> 4;
  const int bm = blockIdx.x * 64;
  const int bn = blockIdx.y * 64;
  float acc[4][4] = {};
  for (int k0 = 0; k0 < K; k0 += 64) {
    #pragma unroll
    for (int i = 0; i < 4; ++i) {  // stage X^T: 64 rows x 64 k
      int idx = tid + i * 256;     // float4 slot, 16 per row
      int r = idx >> 4;
      int kq = idx & 15;
      int rr = bm + r;
      if (rr >= M) rr = M - 1;
      const float4 v = *(const float4*)(X + (size_t)rr * K + k0 + kq * 4);
      xT[kq * 4 + 0][r] = v.x;
      xT[kq * 4 + 1][r] = v.y;
      xT[kq * 4 + 2][r] = v.z;
      xT[kq * 4 + 3][r] = v.w;
    }
    #pragma unroll
    for (int i = 0; i < 4; ++i) {  // stage W: 64 k x 64 cols
      int idx = tid + i * 256;
      int kk = idx >> 4;
      int cq = idx & 15;
      *(float4*)&ws[kk][cq * 4] = *(const float4*)(W + (size_t)(k0 + kk) * NC + bn + cq * 4);
    }
    __syncthreads();
    #pragma unroll 8
    for (int k = 0; k < 64; ++k) {
      float4 a = *(const float4*)&xT[k][ty * 4];
      float4 b = *(const float4*)&ws[k][tx * 4];
      float av[4] = {a.x, a.y, a.z, a.w};
      float bv[4] = {b.x, b.y, b.z, b.w};
      #pragma unroll
      for (int i = 0; i < 4; ++i)
        #pragma unroll
        for (int j = 0; j < 4; ++j) acc[i][j] = fmaf(av[i], bv[j], acc[i][j]);
    }
    __syncthreads();
  }
  #pragma unroll
  for (int i = 0; i < 4; ++i) {
    int r = bm + ty * 4 + i;
    if (r < M) {
      float dn = dinv[r];
      float4 o = make_float4(acc[i][0] * dn, acc[i][1] * dn, acc[i][2] * dn, acc[i][3] * dn);
      *(float4*)(O + (size_t)r * NC + bn + tx * 4) = o;
    }
  }
}

// Layer-1 aggregation: 128 feats, wave per node, lane owns float2. ReLU fused.
__global__ __launch_bounds__(256) void k_agg128(
    const float* __restrict__ A, const int* __restrict__ csr,
    const int* __restrict__ offs, const int* __restrict__ deg,
    const float* __restrict__ dinv, const float* __restrict__ bias,
    float* __restrict__ Bout, int N) {
  int wave = threadIdx.x >> 6;
  int lane = threadIdx.x & 63;
  int node = blockIdx.x * 4 + wave;
  if (node >= N) return;
  int start = offs[node];
  int cnt = deg[node];
  const float2* Af = (const float2*)A;
  float2 acc = make_float2(0.f, 0.f);
  for (int j = 0; j < cnt; ++j) {
    int s = csr[start + j];
    float2 v = Af[(size_t)s * 64 + lane];
    acc.x += v.x;
    acc.y += v.y;
  }
  float2 v = Af[(size_t)node * 64 + lane];  // self loop (A already has dinv[src])
  acc.x += v.x;
  acc.y += v.y;
  float dn = dinv[node];
  float2 bb = ((const float2*)bias)[lane];
  float ox = fmaxf(acc.x * dn + bb.x, 0.f);
  float oy = fmaxf(acc.y * dn + bb.y, 0.f);
  ((float2*)Bout)[(size_t)node * 64 + lane] = make_float2(ox, oy);
}

// Layer-2 aggregation: 64 feats, wave per node, lane owns 1 float. No ReLU.
__global__ __launch_bounds__(256) void k_agg64(
    const float* __restrict__ A, const int* __restrict__ csr,
    const int* __restrict__ offs, const int* __restrict__ deg,
    const float* __restrict__ dinv, const float* __restrict__ bias,
    float* __restrict__ Out, int N) {
  int wave = threadIdx.x >> 6;
  int lane = threadIdx.x & 63;
  int node = blockIdx.x * 4 + wave;
  if (node >= N) return;
  int start = offs[node];
  int cnt = deg[node];
  float acc = 0.f;
  for (int j = 0; j < cnt; ++j) {
    int s = csr[start + j];
    acc += A[(size_t)s * 64 + lane];
  }
  acc += A[(size_t)node * 64 + lane];
  Out[(size_t)node * 64 + lane] = acc * dinv[node] + bias[lane];
}

extern "C" void kernel_launch(void* const* d_in, const int* in_sizes, int n_in,
                              void* d_out, int out_size, void* d_ws, size_t ws_size,
                              hipStream_t stream) {
  const float* x = (const float*)d_in[0];
  const int* ei = (const int*)d_in[1];
  const float* W1 = (const float*)d_in[2];
  const float* b1 = (const float*)d_in[3];
  const float* W2 = (const float*)d_in[4];
  const float* b2 = (const float*)d_in[5];
  float* out = (float*)d_out;

  const int N = in_sizes[0] / 128;  // 50000
  const int E = in_sizes[1] / 2;    // 1600000
  const int* src = ei;
  const int* dst = ei + E;

  // workspace layout (all 4B types)
  float* A = (float*)d_ws;               // N*128  (H1s, later H2s)
  float* B = A + (size_t)N * 128;        // N*128  (h after ReLU)
  int* csr = (int*)(B + (size_t)N * 128);  // E
  int* deg = csr + E;                    // N
  int* cursor = deg + N;                 // N
  int* offs = cursor + N;                // N
  float* dinv = (float*)(offs + N);      // N
  int* bsum = (int*)(dinv + N);          // <=64

  hipMemsetAsync(deg, 0, (size_t)N * sizeof(int), stream);
  k_count<<<(E + 255) / 256, 256, 0, stream>>>(dst, E, deg);
  int nb = (N + 1023) / 1024;
  k_scanA<<<nb, 1024, 0, stream>>>(deg, N, offs, bsum);
  k_scanB<<<1, 64, 0, stream>>>(bsum, nb);
  k_scanC<<<(N + 255) / 256, 256, 0, stream>>>(deg, bsum, N, offs, cursor, dinv);
  k_fill<<<(E + 255) / 256, 256, 0, stream>>>(src, dst, E, cursor, csr);

  dim3 g1((N + 63) / 64, 2);
  k_gemm_scaled<<<g1, 256, 0, stream>>>(x, W1, dinv, A, N, 128, 128);
  k_agg128<<<(N + 3) / 4, 256, 0, stream>>>(A, csr, offs, deg, dinv, b1, B, N);
  dim3 g2((N + 63) / 64, 1);
  k_gemm_scaled<<<g2, 256, 0, stream>>>(B, W2, dinv, A, N, 128, 64);
  k_agg64<<<(N + 3) / 4, 256, 0, stream>>>(A, csr, offs, deg, dinv, b2, out, N);
}

// Round 2
// 424.621 us; speedup vs baseline: 1.3091x; 1.3091x over previous
//
#include <hip/hip_runtime.h>
#include <math.h>

// ---------------------------------------------------------------------------
// 2-layer GCN: out = ReLU(N(x@W1)+b1) -> N(h@W2)+b2, N(.) = D^-1/2 (A+I) D^-1/2
// Fold dinv[src] into GEMM epilogue, dinv[dst] into agg epilogue.
// CSR by dst (counting sort) -> wave-per-node gather, unroll-8 for ILP.
// ---------------------------------------------------------------------------

__global__ __launch_bounds__(256) void k_count(const int* __restrict__ dst, int E,
                                               int* __restrict__ deg) {
  int e = blockIdx.x * 256 + threadIdx.x;
  if (e < E) atomicAdd(&deg[dst[e]], 1);
}

__global__ __launch_bounds__(1024) void k_scanA(const int* __restrict__ deg, int N,
                                                int* __restrict__ offs,
                                                int* __restrict__ bsum) {
  __shared__ int sd[1024];
  int tid = threadIdx.x;
  int i = blockIdx.x * 1024 + tid;
  int v = (i < N) ? deg[i] : 0;
  sd[tid] = v;
  __syncthreads();
  for (int off = 1; off < 1024; off <<= 1) {
    int t = (tid >= off) ? sd[tid - off] : 0;
    __syncthreads();
    sd[tid] += t;
    __syncthreads();
  }
  if (i < N) offs[i] = sd[tid] - v;  // block-local exclusive
  if (tid == 1023) bsum[blockIdx.x] = sd[1023];
}

__global__ void k_scanB(int* bsum, int nb) {  // 1 block x 64, nb <= 64
  int lane = threadIdx.x;
  int v = (lane < nb) ? bsum[lane] : 0;
  int orig = v;
  for (int off = 1; off < 64; off <<= 1) {
    int t = __shfl_up(v, off, 64);
    if (lane >= off) v += t;
  }
  if (lane < nb) bsum[lane] = v - orig;  // exclusive
}

__global__ __launch_bounds__(256) void k_scanC(const int* __restrict__ deg,
                                               const int* __restrict__ bsum, int N,
                                               int* __restrict__ offs,
                                               int* __restrict__ cursor,
                                               float* __restrict__ dinv) {
  int i = blockIdx.x * 256 + threadIdx.x;
  if (i < N) {
    int o = offs[i] + bsum[i >> 10];
    offs[i] = o;
    cursor[i] = o;
    dinv[i] = rsqrtf((float)(deg[i] + 1));  // +1 = self loop
  }
}

__global__ __launch_bounds__(256) void k_fill(const int* __restrict__ src,
                                              const int* __restrict__ dstv, int E,
                                              int* __restrict__ cursor,
                                              int* __restrict__ csr) {
  int e = blockIdx.x * 256 + threadIdx.x;
  if (e < E) {
    int p = atomicAdd(&cursor[dstv[e]], 1);
    csr[p] = src[e];
  }
}

// O[r][c] = (sum_k X[r][k] W[k][c]) * dinv[r].  64x64 tile, BK=64, 4x4 micro.
__global__ __launch_bounds__(256) void k_gemm_scaled(
    const float* __restrict__ X, const float* __restrict__ W,
    const float* __restrict__ dinv, float* __restrict__ O,
    int M, int K, int NC) {
  __shared__ float xT[64][68];
  __shared__ float ws[64][64];
  const int tid = threadIdx.x;
  const int tx = tid & 15;
  const int ty = tid >> 4;
  const int bm = blockIdx.x * 64;
  const int bn = blockIdx.y * 64;
  float acc[4][4] = {};
  for (int k0 = 0; k0 < K; k0 += 64) {
    #pragma unroll
    for (int i = 0; i < 4; ++i) {  // stage X^T: 64 rows x 64 k
      int idx = tid + i * 256;
      int r = idx >> 4;
      int kq = idx & 15;
      int rr = bm + r;
      if (rr >= M) rr = M - 1;
      const float4 v = *(const float4*)(X + (size_t)rr * K + k0 + kq * 4);
      xT[kq * 4 + 0][r] = v.x;
      xT[kq * 4 + 1][r] = v.y;
      xT[kq * 4 + 2][r] = v.z;
      xT[kq * 4 + 3][r] = v.w;
    }
    #pragma unroll
    for (int i = 0; i < 4; ++i) {  // stage W: 64 k x 64 cols
      int idx = tid + i * 256;
      int kk = idx >> 4;
      int cq = idx & 15;
      *(float4*)&ws[kk][cq * 4] = *(const float4*)(W + (size_t)(k0 + kk) * NC + bn + cq * 4);
    }
    __syncthreads();
    #pragma unroll 8
    for (int k = 0; k < 64; ++k) {
      float4 a = *(const float4*)&xT[k][ty * 4];
      float4 b = *(const float4*)&ws[k][tx * 4];
      float av[4] = {a.x, a.y, a.z, a.w};
      float bv[4] = {b.x, b.y, b.z, b.w};
      #pragma unroll
      for (int i = 0; i < 4; ++i)
        #pragma unroll
        for (int j = 0; j < 4; ++j) acc[i][j] = fmaf(av[i], bv[j], acc[i][j]);
    }
    __syncthreads();
  }
  #pragma unroll
  for (int i = 0; i < 4; ++i) {
    int r = bm + ty * 4 + i;
    if (r < M) {
      float dn = dinv[r];
      float4 o = make_float4(acc[i][0] * dn, acc[i][1] * dn, acc[i][2] * dn, acc[i][3] * dn);
      *(float4*)(O + (size_t)r * NC + bn + tx * 4) = o;
    }
  }
}

// Layer-1 aggregation: 128 feats, wave per node, lane owns float2.
// Unroll-8: 8 independent gathers in flight per wave (latency hiding).
__global__ __launch_bounds__(256) void k_agg128(
    const float* __restrict__ A, const int* __restrict__ csr,
    const int* __restrict__ offs, const int* __restrict__ deg,
    const float* __restrict__ dinv, const float* __restrict__ bias,
    float* __restrict__ Bout, int N) {
  int wave = threadIdx.x >> 6;
  int lane = threadIdx.x & 63;
  int node = blockIdx.x * 4 + wave;
  if (node >= N) return;
  int start = offs[node];
  int cnt = deg[node];
  const float2* Af = (const float2*)A;
  float2 a0 = Af[(size_t)node * 64 + lane];  // self loop
  float2 a1 = {0.f, 0.f}, a2 = {0.f, 0.f}, a3 = {0.f, 0.f};
  float2 a4 = {0.f, 0.f}, a5 = {0.f, 0.f}, a6 = {0.f, 0.f}, a7 = {0.f, 0.f};
  int j = 0;
  for (; j + 8 <= cnt; j += 8) {
    int s0 = csr[start + j + 0], s1 = csr[start + j + 1];
    int s2 = csr[start + j + 2], s3 = csr[start + j + 3];
    int s4 = csr[start + j + 4], s5 = csr[start + j + 5];
    int s6 = csr[start + j + 6], s7 = csr[start + j + 7];
    float2 v0 = Af[(size_t)s0 * 64 + lane];
    float2 v1 = Af[(size_t)s1 * 64 + lane];
    float2 v2 = Af[(size_t)s2 * 64 + lane];
    float2 v3 = Af[(size_t)s3 * 64 + lane];
    float2 v4 = Af[(size_t)s4 * 64 + lane];
    float2 v5 = Af[(size_t)s5 * 64 + lane];
    float2 v6 = Af[(size_t)s6 * 64 + lane];
    float2 v7 = Af[(size_t)s7 * 64 + lane];
    a0.x += v0.x; a0.y += v0.y;
    a1.x += v1.x; a1.y += v1.y;
    a2.x += v2.x; a2.y += v2.y;
    a3.x += v3.x; a3.y += v3.y;
    a4.x += v4.x; a4.y += v4.y;
    a5.x += v5.x; a5.y += v5.y;
    a6.x += v6.x; a6.y += v6.y;
    a7.x += v7.x; a7.y += v7.y;
  }
  for (; j < cnt; ++j) {
    int s = csr[start + j];
    float2 v = Af[(size_t)s * 64 + lane];
    a0.x += v.x; a0.y += v.y;
  }
  a0.x += a1.x; a0.y += a1.y;
  a2.x += a3.x; a2.y += a3.y;
  a4.x += a5.x; a4.y += a5.y;
  a6.x += a7.x; a6.y += a7.y;
  a0.x += a2.x; a0.y += a2.y;
  a4.x += a6.x; a4.y += a6.y;
  a0.x += a4.x; a0.y += a4.y;
  float dn = dinv[node];
  float2 bb = ((const float2*)bias)[lane];
  float ox = fmaxf(a0.x * dn + bb.x, 0.f);
  float oy = fmaxf(a0.y * dn + bb.y, 0.f);
  ((float2*)Bout)[(size_t)node * 64 + lane] = make_float2(ox, oy);
}

// Layer-2 aggregation: 64 feats, wave per node, lane owns 1 float. Unroll-8.
__global__ __launch_bounds__(256) void k_agg64(
    const float* __restrict__ A, const int* __restrict__ csr,
    const int* __restrict__ offs, const int* __restrict__ deg,
    const float* __restrict__ dinv, const float* __restrict__ bias,
    float* __restrict__ Out, int N) {
  int wave = threadIdx.x >> 6;
  int lane = threadIdx.x & 63;
  int node = blockIdx.x * 4 + wave;
  if (node >= N) return;
  int start = offs[node];
  int cnt = deg[node];
  float a0 = A[(size_t)node * 64 + lane];  // self loop
  float a1 = 0.f, a2 = 0.f, a3 = 0.f, a4 = 0.f, a5 = 0.f, a6 = 0.f, a7 = 0.f;
  int j = 0;
  for (; j + 8 <= cnt; j += 8) {
    int s0 = csr[start + j + 0], s1 = csr[start + j + 1];
    int s2 = csr[start + j + 2], s3 = csr[start + j + 3];
    int s4 = csr[start + j + 4], s5 = csr[start + j + 5];
    int s6 = csr[start + j + 6], s7 = csr[start + j + 7];
    a0 += A[(size_t)s0 * 64 + lane];
    a1 += A[(size_t)s1 * 64 + lane];
    a2 += A[(size_t)s2 * 64 + lane];
    a3 += A[(size_t)s3 * 64 + lane];
    a4 += A[(size_t)s4 * 64 + lane];
    a5 += A[(size_t)s5 * 64 + lane];
    a6 += A[(size_t)s6 * 64 + lane];
    a7 += A[(size_t)s7 * 64 + lane];
  }
  for (; j < cnt; ++j) a0 += A[(size_t)csr[start + j] * 64 + lane];
  a0 = ((a0 + a1) + (a2 + a3)) + ((a4 + a5) + (a6 + a7));
  Out[(size_t)node * 64 + lane] = a0 * dinv[node] + bias[lane];
}

extern "C" void kernel_launch(void* const* d_in, const int* in_sizes, int n_in,
                              void* d_out, int out_size, void* d_ws, size_t ws_size,
                              hipStream_t stream) {
  const float* x = (const float*)d_in[0];
  const int* ei = (const int*)d_in[1];
  const float* W1 = (const float*)d_in[2];
  const float* b1 = (const float*)d_in[3];
  const float* W2 = (const float*)d_in[4];
  const float* b2 = (const float*)d_in[5];
  float* out = (float*)d_out;

  const int N = in_sizes[0] / 128;  // 50000
  const int E = in_sizes[1] / 2;    // 1600000
  const int* src = ei;
  const int* dst = ei + E;

  // workspace layout (all 4B types)
  float* A = (float*)d_ws;                 // N*128  (H1s, later H2s)
  float* B = A + (size_t)N * 128;          // N*128  (h after ReLU)
  int* csr = (int*)(B + (size_t)N * 128);  // E
  int* deg = csr + E;                      // N
  int* cursor = deg + N;                   // N
  int* offs = cursor + N;                  // N
  float* dinv = (float*)(offs + N);        // N
  int* bsum = (int*)(dinv + N);            // <=64

  hipMemsetAsync(deg, 0, (size_t)N * sizeof(int), stream);
  k_count<<<(E + 255) / 256, 256, 0, stream>>>(dst, E, deg);
  int nb = (N + 1023) / 1024;
  k_scanA<<<nb, 1024, 0, stream>>>(deg, N, offs, bsum);
  k_scanB<<<1, 64, 0, stream>>>(bsum, nb);
  k_scanC<<<(N + 255) / 256, 256, 0, stream>>>(deg, bsum, N, offs, cursor, dinv);
  k_fill<<<(E + 255) / 256, 256, 0, stream>>>(src, dst, E, cursor, csr);

  dim3 g1((N + 63) / 64, 2);
  k_gemm_scaled<<<g1, 256, 0, stream>>>(x, W1, dinv, A, N, 128, 128);
  k_agg128<<<(N + 3) / 4, 256, 0, stream>>>(A, csr, offs, deg, dinv, b1, B, N);
  dim3 g2((N + 63) / 64, 1);
  k_gemm_scaled<<<g2, 256, 0, stream>>>(B, W2, dinv, A, N, 128, 64);
  k_agg64<<<(N + 3) / 4, 256, 0, stream>>>(A, csr, offs, deg, dinv, b2, out, N);
}

// Round 3
// 263.437 us; speedup vs baseline: 2.1100x; 1.6118x over previous
//
#include <hip/hip_runtime.h>
#include <math.h>

// ---------------------------------------------------------------------------
// 2-layer GCN: out = ReLU(N(x@W1)+b1) -> N(h@W2)+b2, N(.) = D^-1/2 (A+I) D^-1/2
// dinv[src] folded into GEMM epilogue, dinv[dst] into agg epilogue.
// CSR built via two-level bucket partition (no global atomics, write-local):
//   kA: per-(bucket,block) counts  ->  scan  ->  kC: coalesced pair binning
//   kD: per-bucket LDS sort -> deg/offs/dinv/csr (block-private writes).
// Aggregation: wave-per-node gather, unroll-8 for ILP.
// ---------------------------------------------------------------------------

#define CH 8192        // edges per partition block
#define BSH 6          // bucket shift: 64 nodes per bucket
#define NBMAX 1024     // LDS histogram capacity (buckets <= 1024)

__global__ __launch_bounds__(256) void kA_count(const int* __restrict__ dst, int E,
                                                int NB, int NBLK,
                                                int* __restrict__ cnt) {
  __shared__ int h[NBMAX];
  int t = threadIdx.x;
  int blk = blockIdx.x;
  for (int i = t; i < NB; i += 256) h[i] = 0;
  __syncthreads();
  int e0 = blk * CH;
  int e1 = min(E, e0 + CH);
  for (int e = e0 + t; e < e1; e += 256) atomicAdd(&h[dst[e] >> BSH], 1);
  __syncthreads();
  for (int i = t; i < NB; i += 256) cnt[i * NBLK + blk] = h[i];
}

__global__ __launch_bounds__(1024) void k_scanA(const int* __restrict__ in, int M,
                                                int* __restrict__ out,
                                                int* __restrict__ bsum) {
  __shared__ int sd[1024];
  int tid = threadIdx.x;
  int i = blockIdx.x * 1024 + tid;
  int v = (i < M) ? in[i] : 0;
  sd[tid] = v;
  __syncthreads();
  for (int off = 1; off < 1024; off <<= 1) {
    int t = (tid >= off) ? sd[tid - off] : 0;
    __syncthreads();
    sd[tid] += t;
    __syncthreads();
  }
  if (i < M) out[i] = sd[tid] - v;  // block-local exclusive
  if (tid == 1023) bsum[blockIdx.x] = sd[1023];
}

__global__ __launch_bounds__(1024) void k_scanB(int* __restrict__ b, int nb) {
  __shared__ int sd[1024];
  int t = threadIdx.x;
  int v = (t < nb) ? b[t] : 0;
  sd[t] = v;
  __syncthreads();
  for (int off = 1; off < 1024; off <<= 1) {
    int tmp = (t >= off) ? sd[t - off] : 0;
    __syncthreads();
    sd[t] += tmp;
    __syncthreads();
  }
  if (t < nb) b[t] = sd[t] - v;  // exclusive
}

__global__ __launch_bounds__(256) void kC_scatter(const int* __restrict__ src,
                                                  const int* __restrict__ dst, int E,
                                                  int NB, int NBLK,
                                                  const int* __restrict__ pos,
                                                  const int* __restrict__ bsum,
                                                  int2* __restrict__ pairs) {
  __shared__ int lcur[NBMAX];
  int t = threadIdx.x;
  int blk = blockIdx.x;
  for (int i = t; i < NB; i += 256) {
    int f = i * NBLK + blk;
    lcur[i] = pos[f] + bsum[f >> 10];
  }
  __syncthreads();
  int e0 = blk * CH;
  int e1 = min(E, e0 + CH);
  for (int e = e0 + t; e < e1; e += 256) {
    int d = dst[e];
    int p = atomicAdd(&lcur[d >> BSH], 1);
    pairs[p] = make_int2(d, src[e]);
  }
}

// One block per bucket: per-node deg (LDS hist) -> LDS scan -> deg/offs/dinv,
// then scatter csr within the bucket's private region.
__global__ __launch_bounds__(256) void kD_build(const int2* __restrict__ pairs,
                                                const int* __restrict__ pos,
                                                const int* __restrict__ bsum,
                                                int N, int E, int NB, int NBLK,
                                                int* __restrict__ csr,
                                                int* __restrict__ deg,
                                                int* __restrict__ offs,
                                                float* __restrict__ dinv) {
  __shared__ int ldeg[64];
  __shared__ int lsc[64];
  __shared__ int lcur[64];
  int t = threadIdx.x;
  int q = blockIdx.x;
  int node_lo = q << BSH;
  int f0 = q * NBLK;
  int base = pos[f0] + bsum[f0 >> 10];
  int end;
  if (q == NB - 1) end = E;
  else {
    int f1 = (q + 1) * NBLK;
    end = pos[f1] + bsum[f1 >> 10];
  }
  if (t < 64) ldeg[t] = 0;
  __syncthreads();
  for (int e = base + t; e < end; e += 256)
    atomicAdd(&ldeg[pairs[e].x - node_lo], 1);
  __syncthreads();
  // exclusive scan of ldeg[0..63]
  int v = (t < 64) ? ldeg[t] : 0;
  if (t < 64) lsc[t] = v;
  __syncthreads();
  for (int off = 1; off < 64; off <<= 1) {
    int tmp = (t < 64 && t >= off) ? lsc[t - off] : 0;
    __syncthreads();
    if (t < 64) lsc[t] += tmp;
    __syncthreads();
  }
  if (t < 64) {
    int ex = lsc[t] - v;
    lcur[t] = ex;
    int g = node_lo + t;
    if (g < N) {
      deg[g] = v;
      offs[g] = base + ex;
      dinv[g] = rsqrtf((float)(v + 1));  // +1 self loop
    }
  }
  __syncthreads();
  for (int e = base + t; e < end; e += 256) {
    int2 pr = pairs[e];
    int p = atomicAdd(&lcur[pr.x - node_lo], 1);
    csr[base + p] = pr.y;
  }
}

// O[r][c] = (sum_k X[r][k] W[k][c]) * dinv[r].  64x64 tile, BK=64, 4x4 micro.
__global__ __launch_bounds__(256) void k_gemm_scaled(
    const float* __restrict__ X, const float* __restrict__ W,
    const float* __restrict__ dinv, float* __restrict__ O,
    int M, int K, int NC) {
  __shared__ float xT[64][68];
  __shared__ float ws[64][64];
  const int tid = threadIdx.x;
  const int tx = tid & 15;
  const int ty = tid >> 4;
  const int bm = blockIdx.x * 64;
  const int bn = blockIdx.y * 64;
  float acc[4][4] = {};
  for (int k0 = 0; k0 < K; k0 += 64) {
    #pragma unroll
    for (int i = 0; i < 4; ++i) {
      int idx = tid + i * 256;
      int r = idx >> 4;
      int kq = idx & 15;
      int rr = bm + r;
      if (rr >= M) rr = M - 1;
      const float4 v = *(const float4*)(X + (size_t)rr * K + k0 + kq * 4);
      xT[kq * 4 + 0][r] = v.x;
      xT[kq * 4 + 1][r] = v.y;
      xT[kq * 4 + 2][r] = v.z;
      xT[kq * 4 + 3][r] = v.w;
    }
    #pragma unroll
    for (int i = 0; i < 4; ++i) {
      int idx = tid + i * 256;
      int kk = idx >> 4;
      int cq = idx & 15;
      *(float4*)&ws[kk][cq * 4] = *(const float4*)(W + (size_t)(k0 + kk) * NC + bn + cq * 4);
    }
    __syncthreads();
    #pragma unroll 8
    for (int k = 0; k < 64; ++k) {
      float4 a = *(const float4*)&xT[k][ty * 4];
      float4 b = *(const float4*)&ws[k][tx * 4];
      float av[4] = {a.x, a.y, a.z, a.w};
      float bv[4] = {b.x, b.y, b.z, b.w};
      #pragma unroll
      for (int i = 0; i < 4; ++i)
        #pragma unroll
        for (int j = 0; j < 4; ++j) acc[i][j] = fmaf(av[i], bv[j], acc[i][j]);
    }
    __syncthreads();
  }
  #pragma unroll
  for (int i = 0; i < 4; ++i) {
    int r = bm + ty * 4 + i;
    if (r < M) {
      float dn = dinv[r];
      float4 o = make_float4(acc[i][0] * dn, acc[i][1] * dn, acc[i][2] * dn, acc[i][3] * dn);
      *(float4*)(O + (size_t)r * NC + bn + tx * 4) = o;
    }
  }
}

// Layer-1 aggregation: 128 feats, wave per node, lane owns float2. Unroll-8.
__global__ __launch_bounds__(256) void k_agg128(
    const float* __restrict__ A, const int* __restrict__ csr,
    const int* __restrict__ offs, const int* __restrict__ deg,
    const float* __restrict__ dinv, const float* __restrict__ bias,
    float* __restrict__ Bout, int N) {
  int wave = threadIdx.x >> 6;
  int lane = threadIdx.x & 63;
  int node = blockIdx.x * 4 + wave;
  if (node >= N) return;
  int start = offs[node];
  int cnt = deg[node];
  const float2* Af = (const float2*)A;
  float2 a0 = Af[(size_t)node * 64 + lane];  // self loop
  float2 a1 = {0.f, 0.f}, a2 = {0.f, 0.f}, a3 = {0.f, 0.f};
  float2 a4 = {0.f, 0.f}, a5 = {0.f, 0.f}, a6 = {0.f, 0.f}, a7 = {0.f, 0.f};
  int j = 0;
  for (; j + 8 <= cnt; j += 8) {
    int s0 = csr[start + j + 0], s1 = csr[start + j + 1];
    int s2 = csr[start + j + 2], s3 = csr[start + j + 3];
    int s4 = csr[start + j + 4], s5 = csr[start + j + 5];
    int s6 = csr[start + j + 6], s7 = csr[start + j + 7];
    float2 v0 = Af[(size_t)s0 * 64 + lane];
    float2 v1 = Af[(size_t)s1 * 64 + lane];
    float2 v2 = Af[(size_t)s2 * 64 + lane];
    float2 v3 = Af[(size_t)s3 * 64 + lane];
    float2 v4 = Af[(size_t)s4 * 64 + lane];
    float2 v5 = Af[(size_t)s5 * 64 + lane];
    float2 v6 = Af[(size_t)s6 * 64 + lane];
    float2 v7 = Af[(size_t)s7 * 64 + lane];
    a0.x += v0.x; a0.y += v0.y;
    a1.x += v1.x; a1.y += v1.y;
    a2.x += v2.x; a2.y += v2.y;
    a3.x += v3.x; a3.y += v3.y;
    a4.x += v4.x; a4.y += v4.y;
    a5.x += v5.x; a5.y += v5.y;
    a6.x += v6.x; a6.y += v6.y;
    a7.x += v7.x; a7.y += v7.y;
  }
  for (; j < cnt; ++j) {
    int s = csr[start + j];
    float2 v = Af[(size_t)s * 64 + lane];
    a0.x += v.x; a0.y += v.y;
  }
  a0.x += a1.x; a0.y += a1.y;
  a2.x += a3.x; a2.y += a3.y;
  a4.x += a5.x; a4.y += a5.y;
  a6.x += a7.x; a6.y += a7.y;
  a0.x += a2.x; a0.y += a2.y;
  a4.x += a6.x; a4.y += a6.y;
  a0.x += a4.x; a0.y += a4.y;
  float dn = dinv[node];
  float2 bb = ((const float2*)bias)[lane];
  float ox = fmaxf(a0.x * dn + bb.x, 0.f);
  float oy = fmaxf(a0.y * dn + bb.y, 0.f);
  ((float2*)Bout)[(size_t)node * 64 + lane] = make_float2(ox, oy);
}

// Layer-2 aggregation: 64 feats, wave per node, lane owns 1 float. Unroll-8.
__global__ __launch_bounds__(256) void k_agg64(
    const float* __restrict__ A, const int* __restrict__ csr,
    const int* __restrict__ offs, const int* __restrict__ deg,
    const float* __restrict__ dinv, const float* __restrict__ bias,
    float* __restrict__ Out, int N) {
  int wave = threadIdx.x >> 6;
  int lane = threadIdx.x & 63;
  int node = blockIdx.x * 4 + wave;
  if (node >= N) return;
  int start = offs[node];
  int cnt = deg[node];
  float a0 = A[(size_t)node * 64 + lane];  // self loop
  float a1 = 0.f, a2 = 0.f, a3 = 0.f, a4 = 0.f, a5 = 0.f, a6 = 0.f, a7 = 0.f;
  int j = 0;
  for (; j + 8 <= cnt; j += 8) {
    int s0 = csr[start + j + 0], s1 = csr[start + j + 1];
    int s2 = csr[start + j + 2], s3 = csr[start + j + 3];
    int s4 = csr[start + j + 4], s5 = csr[start + j + 5];
    int s6 = csr[start + j + 6], s7 = csr[start + j + 7];
    a0 += A[(size_t)s0 * 64 + lane];
    a1 += A[(size_t)s1 * 64 + lane];
    a2 += A[(size_t)s2 * 64 + lane];
    a3 += A[(size_t)s3 * 64 + lane];
    a4 += A[(size_t)s4 * 64 + lane];
    a5 += A[(size_t)s5 * 64 + lane];
    a6 += A[(size_t)s6 * 64 + lane];
    a7 += A[(size_t)s7 * 64 + lane];
  }
  for (; j < cnt; ++j) a0 += A[(size_t)csr[start + j] * 64 + lane];
  a0 = ((a0 + a1) + (a2 + a3)) + ((a4 + a5) + (a6 + a7));
  Out[(size_t)node * 64 + lane] = a0 * dinv[node] + bias[lane];
}

extern "C" void kernel_launch(void* const* d_in, const int* in_sizes, int n_in,
                              void* d_out, int out_size, void* d_ws, size_t ws_size,
                              hipStream_t stream) {
  const float* x = (const float*)d_in[0];
  const int* ei = (const int*)d_in[1];
  const float* W1 = (const float*)d_in[2];
  const float* b1 = (const float*)d_in[3];
  const float* W2 = (const float*)d_in[4];
  const float* b2 = (const float*)d_in[5];
  float* out = (float*)d_out;

  const int N = in_sizes[0] / 128;  // 50000
  const int E = in_sizes[1] / 2;    // 1600000
  const int* src = ei;
  const int* dst = ei + E;

  const int NB = (N + (1 << BSH) - 1) >> BSH;   // buckets (782)
  const int NBLK = (E + CH - 1) / CH;           // partition blocks (196)
  const int M = NB * NBLK;                      // count-table entries
  const int NSB = (M + 1023) / 1024;            // scan blocks

  // workspace layout (aliased: tables live in A, pairs live in B; both dead
  // before GEMM1/agg write those regions)
  float* A = (float*)d_ws;                 // N*128 floats
  float* B = A + (size_t)N * 128;          // N*128 floats
  int* csr = (int*)(B + (size_t)N * 128);  // E ints
  int* deg = csr + E;                      // N
  int* offs = deg + N;                     // N
  float* dinv = (float*)(offs + N);        // N
  int* cnt = (int*)A;                      // M (alias A)
  int* pos = cnt + M;                      // M (alias A)
  int* bsum = pos + M;                     // <=1024 (alias A)
  int2* pairs = (int2*)B;                  // E pairs (alias B)

  kA_count<<<NBLK, 256, 0, stream>>>(dst, E, NB, NBLK, cnt);
  k_scanA<<<NSB, 1024, 0, stream>>>(cnt, M, pos, bsum);
  k_scanB<<<1, 1024, 0, stream>>>(bsum, NSB);
  kC_scatter<<<NBLK, 256, 0, stream>>>(src, dst, E, NB, NBLK, pos, bsum, pairs);
  kD_build<<<NB, 256, 0, stream>>>(pairs, pos, bsum, N, E, NB, NBLK,
                                   csr, deg, offs, dinv);

  dim3 g1((N + 63) / 64, 2);
  k_gemm_scaled<<<g1, 256, 0, stream>>>(x, W1, dinv, A, N, 128, 128);
  k_agg128<<<(N + 3) / 4, 256, 0, stream>>>(A, csr, offs, deg, dinv, b1, B, N);
  dim3 g2((N + 63) / 64, 1);
  k_gemm_scaled<<<g2, 256, 0, stream>>>(B, W2, dinv, A, N, 128, 64);
  k_agg64<<<(N + 3) / 4, 256, 0, stream>>>(A, csr, offs, deg, dinv, b2, out, N);
}

// Round 4
// 205.061 us; speedup vs baseline: 2.7107x; 1.2847x over previous
//
#include <hip/hip_runtime.h>
#include <math.h>

// ---------------------------------------------------------------------------
// 2-layer GCN: out = ReLU(N(x@W1)+b1) -> N(h@W2)+b2, N(.) = D^-1/2 (A+I) D^-1/2
// dinv[src] folded into GEMM epilogue, dinv[dst] into agg epilogue.
// Gather tables stored in bf16 (rows halve -> half the 64B lines per edge);
// fp32 accumulation. Dummy zero row at index N pads self-loop/remainders.
// CSR built via two-level bucket partition (no global atomics, write-local).
// ---------------------------------------------------------------------------

#define CH 8192        // edges per partition block
#define BSH 6          // bucket shift: 64 nodes per bucket
#define NBMAX 1024     // LDS histogram capacity (buckets <= 1024)

static __device__ __forceinline__ float bflo(unsigned u) { return __uint_as_float(u << 16); }
static __device__ __forceinline__ float bfhi(unsigned u) { return __uint_as_float(u & 0xffff0000u); }
static __device__ __forceinline__ unsigned short f2bf(float f) {
  unsigned u = __float_as_uint(f);
  return (unsigned short)((u + 0x7fffu + ((u >> 16) & 1u)) >> 16);  // RNE
}
static __device__ __forceinline__ unsigned packbf(float a, float b) {
  return (unsigned)f2bf(a) | ((unsigned)f2bf(b) << 16);
}
static __device__ __forceinline__ void accum(float4& a, uint2 v) {
  a.x += bflo(v.x); a.y += bfhi(v.x); a.z += bflo(v.y); a.w += bfhi(v.y);
}

__global__ __launch_bounds__(256) void kA_count(const int* __restrict__ dst, int E,
                                                int NB, int NBLK,
                                                int* __restrict__ cnt) {
  __shared__ int h[NBMAX];
  int t = threadIdx.x;
  int blk = blockIdx.x;
  for (int i = t; i < NB; i += 256) h[i] = 0;
  __syncthreads();
  int e0 = blk * CH;
  int e1 = min(E, e0 + CH);
  for (int e = e0 + t; e < e1; e += 256) atomicAdd(&h[dst[e] >> BSH], 1);
  __syncthreads();
  for (int i = t; i < NB; i += 256) cnt[i * NBLK + blk] = h[i];
}

__global__ __launch_bounds__(1024) void k_scanA(const int* __restrict__ in, int M,
                                                int* __restrict__ out,
                                                int* __restrict__ bsum) {
  __shared__ int sd[1024];
  int tid = threadIdx.x;
  int i = blockIdx.x * 1024 + tid;
  int v = (i < M) ? in[i] : 0;
  sd[tid] = v;
  __syncthreads();
  for (int off = 1; off < 1024; off <<= 1) {
    int t = (tid >= off) ? sd[tid - off] : 0;
    __syncthreads();
    sd[tid] += t;
    __syncthreads();
  }
  if (i < M) out[i] = sd[tid] - v;  // block-local exclusive
  if (tid == 1023) bsum[blockIdx.x] = sd[1023];
}

__global__ __launch_bounds__(1024) void k_scanB(int* __restrict__ b, int nb) {
  __shared__ int sd[1024];
  int t = threadIdx.x;
  int v = (t < nb) ? b[t] : 0;
  sd[t] = v;
  __syncthreads();
  for (int off = 1; off < 1024; off <<= 1) {
    int tmp = (t >= off) ? sd[t - off] : 0;
    __syncthreads();
    sd[t] += tmp;
    __syncthreads();
  }
  if (t < nb) b[t] = sd[t] - v;  // exclusive
}

__global__ __launch_bounds__(256) void kC_scatter(const int* __restrict__ src,
                                                  const int* __restrict__ dst, int E,
                                                  int NB, int NBLK,
                                                  const int* __restrict__ pos,
                                                  const int* __restrict__ bsum,
                                                  int2* __restrict__ pairs) {
  __shared__ int lcur[NBMAX];
  int t = threadIdx.x;
  int blk = blockIdx.x;
  for (int i = t; i < NB; i += 256) {
    int f = i * NBLK + blk;
    lcur[i] = pos[f] + bsum[f >> 10];
  }
  __syncthreads();
  int e0 = blk * CH;
  int e1 = min(E, e0 + CH);
  for (int e = e0 + t; e < e1; e += 256) {
    int d = dst[e];
    int p = atomicAdd(&lcur[d >> BSH], 1);
    pairs[p] = make_int2(d, src[e]);
  }
}

__global__ __launch_bounds__(256) void kD_build(const int2* __restrict__ pairs,
                                                const int* __restrict__ pos,
                                                const int* __restrict__ bsum,
                                                int N, int E, int NB, int NBLK,
                                                int* __restrict__ csr,
                                                int* __restrict__ deg,
                                                int* __restrict__ offs,
                                                float* __restrict__ dinv) {
  __shared__ int ldeg[64];
  __shared__ int lsc[64];
  __shared__ int lcur[64];
  int t = threadIdx.x;
  int q = blockIdx.x;
  int node_lo = q << BSH;
  int f0 = q * NBLK;
  int base = pos[f0] + bsum[f0 >> 10];
  int end;
  if (q == NB - 1) end = E;
  else {
    int f1 = (q + 1) * NBLK;
    end = pos[f1] + bsum[f1 >> 10];
  }
  if (t < 64) ldeg[t] = 0;
  __syncthreads();
  for (int e = base + t; e < end; e += 256)
    atomicAdd(&ldeg[pairs[e].x - node_lo], 1);
  __syncthreads();
  int v = (t < 64) ? ldeg[t] : 0;
  if (t < 64) lsc[t] = v;
  __syncthreads();
  for (int off = 1; off < 64; off <<= 1) {
    int tmp = (t < 64 && t >= off) ? lsc[t - off] : 0;
    __syncthreads();
    if (t < 64) lsc[t] += tmp;
    __syncthreads();
  }
  if (t < 64) {
    int ex = lsc[t] - v;
    lcur[t] = ex;
    int g = node_lo + t;
    if (g < N) {
      deg[g] = v;
      offs[g] = base + ex;
      dinv[g] = rsqrtf((float)(v + 1));  // +1 self loop
    }
  }
  __syncthreads();
  for (int e = base + t; e < end; e += 256) {
    int2 pr = pairs[e];
    int p = atomicAdd(&lcur[pr.x - node_lo], 1);
    csr[base + p] = pr.y;
  }
}

// O[r][c] = (sum_k X[r][k] W[k][c]) * dinv[r], written as bf16 table.
// Rows [M, Mpad) get zeros (dummy row for self-loop/remainder padding).
__global__ __launch_bounds__(256) void k_gemm_bf(
    const float* __restrict__ X, const float* __restrict__ W,
    const float* __restrict__ dinv, unsigned short* __restrict__ O,
    int M, int K, int NC, int Mpad) {
  __shared__ float xT[64][68];
  __shared__ float ws[64][64];
  const int tid = threadIdx.x;
  const int tx = tid & 15;
  const int ty = tid >> 4;
  const int bm = blockIdx.x * 64;
  const int bn = blockIdx.y * 64;
  float acc[4][4] = {};
  for (int k0 = 0; k0 < K; k0 += 64) {
    #pragma unroll
    for (int i = 0; i < 4; ++i) {
      int idx = tid + i * 256;
      int r = idx >> 4;
      int kq = idx & 15;
      int rr = bm + r;
      if (rr >= M) rr = M - 1;
      const float4 v = *(const float4*)(X + (size_t)rr * K + k0 + kq * 4);
      xT[kq * 4 + 0][r] = v.x;
      xT[kq * 4 + 1][r] = v.y;
      xT[kq * 4 + 2][r] = v.z;
      xT[kq * 4 + 3][r] = v.w;
    }
    #pragma unroll
    for (int i = 0; i < 4; ++i) {
      int idx = tid + i * 256;
      int kk = idx >> 4;
      int cq = idx & 15;
      *(float4*)&ws[kk][cq * 4] = *(const float4*)(W + (size_t)(k0 + kk) * NC + bn + cq * 4);
    }
    __syncthreads();
    #pragma unroll 8
    for (int k = 0; k < 64; ++k) {
      float4 a = *(const float4*)&xT[k][ty * 4];
      float4 b = *(const float4*)&ws[k][tx * 4];
      float av[4] = {a.x, a.y, a.z, a.w};
      float bv[4] = {b.x, b.y, b.z, b.w};
      #pragma unroll
      for (int i = 0; i < 4; ++i)
        #pragma unroll
        for (int j = 0; j < 4; ++j) acc[i][j] = fmaf(av[i], bv[j], acc[i][j]);
    }
    __syncthreads();
  }
  #pragma unroll
  for (int i = 0; i < 4; ++i) {
    int r = bm + ty * 4 + i;
    if (r < Mpad) {
      uint2 w = make_uint2(0u, 0u);
      if (r < M) {
        float dn = dinv[r];
        w.x = packbf(acc[i][0] * dn, acc[i][1] * dn);
        w.y = packbf(acc[i][2] * dn, acc[i][3] * dn);
      }
      *(uint2*)(O + (size_t)r * NC + bn + tx * 4) = w;
    }
  }
}

// Layer-1 aggregation: bf16 table rows of 128 feats (64 uints). Half-wave per
// edge row: lanes 0-31 -> even edge, 32-63 -> odd edge, 8B/lane. ReLU fused.
__global__ __launch_bounds__(256) void k_agg128_bf(
    const unsigned* __restrict__ T, const int* __restrict__ csr,
    const int* __restrict__ offs, const int* __restrict__ deg,
    const float* __restrict__ dinv, const float* __restrict__ bias,
    float* __restrict__ Bout, int N) {
  int wave = threadIdx.x >> 6;
  int lane = threadIdx.x & 63;
  int node = blockIdx.x * 4 + wave;
  if (node >= N) return;
  int start = offs[node];
  int cnt = deg[node];
  int half = lane >> 5;
  int fl = lane & 31;  // feature quad: feats fl*4 .. fl*4+3
  const uint2* Tq = (const uint2*)T;  // row = 32 uint2
  float4 a0 = {0, 0, 0, 0}, a1 = {0, 0, 0, 0}, a2 = {0, 0, 0, 0}, a3 = {0, 0, 0, 0};
  float4 a4 = {0, 0, 0, 0}, a5 = {0, 0, 0, 0}, a6 = {0, 0, 0, 0}, a7 = {0, 0, 0, 0};
  {  // self loop on low half, zero row on high half
    int s = half ? N : node;
    accum(a0, Tq[(size_t)s * 32 + fl]);
  }
  int j = 0;
  for (; j + 16 <= cnt; j += 16) {
    int b = start + j + half;
    int s0 = csr[b + 0],  s1 = csr[b + 2],  s2 = csr[b + 4],  s3 = csr[b + 6];
    int s4 = csr[b + 8],  s5 = csr[b + 10], s6 = csr[b + 12], s7 = csr[b + 14];
    uint2 v0 = Tq[(size_t)s0 * 32 + fl];
    uint2 v1 = Tq[(size_t)s1 * 32 + fl];
    uint2 v2 = Tq[(size_t)s2 * 32 + fl];
    uint2 v3 = Tq[(size_t)s3 * 32 + fl];
    uint2 v4 = Tq[(size_t)s4 * 32 + fl];
    uint2 v5 = Tq[(size_t)s5 * 32 + fl];
    uint2 v6 = Tq[(size_t)s6 * 32 + fl];
    uint2 v7 = Tq[(size_t)s7 * 32 + fl];
    accum(a0, v0); accum(a1, v1); accum(a2, v2); accum(a3, v3);
    accum(a4, v4); accum(a5, v5); accum(a6, v6); accum(a7, v7);
  }
  for (; j < cnt; j += 2) {
    int idx = j + half;
    int s = (idx < cnt) ? csr[start + idx] : N;  // dummy zero row pads
    accum(a0, Tq[(size_t)s * 32 + fl]);
  }
  a0.x += a1.x; a0.y += a1.y; a0.z += a1.z; a0.w += a1.w;
  a2.x += a3.x; a2.y += a3.y; a2.z += a3.z; a2.w += a3.w;
  a4.x += a5.x; a4.y += a5.y; a4.z += a5.z; a4.w += a5.w;
  a6.x += a7.x; a6.y += a7.y; a6.z += a7.z; a6.w += a7.w;
  a0.x += a2.x; a0.y += a2.y; a0.z += a2.z; a0.w += a2.w;
  a4.x += a6.x; a4.y += a6.y; a4.z += a6.z; a4.w += a6.w;
  a0.x += a4.x; a0.y += a4.y; a0.z += a4.z; a0.w += a4.w;
  // combine halves
  a0.x += __shfl_xor(a0.x, 32, 64);
  a0.y += __shfl_xor(a0.y, 32, 64);
  a0.z += __shfl_xor(a0.z, 32, 64);
  a0.w += __shfl_xor(a0.w, 32, 64);
  if (half == 0) {
    float dn = dinv[node];
    float4 bb = ((const float4*)bias)[fl];
    float4 o;
    o.x = fmaxf(fmaf(a0.x, dn, bb.x), 0.f);
    o.y = fmaxf(fmaf(a0.y, dn, bb.y), 0.f);
    o.z = fmaxf(fmaf(a0.z, dn, bb.z), 0.f);
    o.w = fmaxf(fmaf(a0.w, dn, bb.w), 0.f);
    ((float4*)Bout)[(size_t)node * 32 + fl] = o;
  }
}

// Layer-2 aggregation: bf16 rows of 64 feats (16 uint2). Quarter-wave per edge
// row: 4 edges in flight per instruction, 8B/lane.
__global__ __launch_bounds__(256) void k_agg64_bf(
    const unsigned* __restrict__ T, const int* __restrict__ csr,
    const int* __restrict__ offs, const int* __restrict__ deg,
    const float* __restrict__ dinv, const float* __restrict__ bias,
    float* __restrict__ Out, int N) {
  int wave = threadIdx.x >> 6;
  int lane = threadIdx.x & 63;
  int node = blockIdx.x * 4 + wave;
  if (node >= N) return;
  int start = offs[node];
  int cnt = deg[node];
  int g = lane >> 4;   // edge slot 0..3
  int fl = lane & 15;  // feature quad: feats fl*4 .. fl*4+3
  const uint2* Tq = (const uint2*)T;  // row = 16 uint2
  float4 a0 = {0, 0, 0, 0}, a1 = {0, 0, 0, 0}, a2 = {0, 0, 0, 0}, a3 = {0, 0, 0, 0};
  {  // self loop on group 0
    int s = (g == 0) ? node : N;
    accum(a0, Tq[(size_t)s * 16 + fl]);
  }
  int j = 0;
  for (; j + 16 <= cnt; j += 16) {
    int b = start + j + g;
    int s0 = csr[b + 0], s1 = csr[b + 4], s2 = csr[b + 8], s3 = csr[b + 12];
    uint2 v0 = Tq[(size_t)s0 * 16 + fl];
    uint2 v1 = Tq[(size_t)s1 * 16 + fl];
    uint2 v2 = Tq[(size_t)s2 * 16 + fl];
    uint2 v3 = Tq[(size_t)s3 * 16 + fl];
    accum(a0, v0); accum(a1, v1); accum(a2, v2); accum(a3, v3);
  }
  for (; j < cnt; j += 4) {
    int idx = j + g;
    int s = (idx < cnt) ? csr[start + idx] : N;
    accum(a0, Tq[(size_t)s * 16 + fl]);
  }
  a0.x += a1.x; a0.y += a1.y; a0.z += a1.z; a0.w += a1.w;
  a2.x += a3.x; a2.y += a3.y; a2.z += a3.z; a2.w += a3.w;
  a0.x += a2.x; a0.y += a2.y; a0.z += a2.z; a0.w += a2.w;
  a0.x += __shfl_xor(a0.x, 32, 64);
  a0.y += __shfl_xor(a0.y, 32, 64);
  a0.z += __shfl_xor(a0.z, 32, 64);
  a0.w += __shfl_xor(a0.w, 32, 64);
  a0.x += __shfl_xor(a0.x, 16, 64);
  a0.y += __shfl_xor(a0.y, 16, 64);
  a0.z += __shfl_xor(a0.z, 16, 64);
  a0.w += __shfl_xor(a0.w, 16, 64);
  if (lane < 16) {
    float dn = dinv[node];
    float4 bb = ((const float4*)bias)[fl];
    float4 o;
    o.x = fmaf(a0.x, dn, bb.x);
    o.y = fmaf(a0.y, dn, bb.y);
    o.z = fmaf(a0.z, dn, bb.z);
    o.w = fmaf(a0.w, dn, bb.w);
    ((float4*)Out)[(size_t)node * 16 + fl] = o;
  }
}

extern "C" void kernel_launch(void* const* d_in, const int* in_sizes, int n_in,
                              void* d_out, int out_size, void* d_ws, size_t ws_size,
                              hipStream_t stream) {
  const float* x = (const float*)d_in[0];
  const int* ei = (const int*)d_in[1];
  const float* W1 = (const float*)d_in[2];
  const float* b1 = (const float*)d_in[3];
  const float* W2 = (const float*)d_in[4];
  const float* b2 = (const float*)d_in[5];
  float* out = (float*)d_out;

  const int N = in_sizes[0] / 128;  // 50000
  const int E = in_sizes[1] / 2;    // 1600000
  const int* src = ei;
  const int* dst = ei + E;

  const int NB = (N + (1 << BSH) - 1) >> BSH;  // buckets (782)
  const int NBLK = (E + CH - 1) / CH;          // partition blocks (196)
  const int M = NB * NBLK;                     // count-table entries
  const int NSB = (M + 1023) / 1024;           // scan blocks

  // workspace layout (aliased; tables live in A region, pairs in B region)
  float* A = (float*)d_ws;                 // N*128 floats region
  float* B = A + (size_t)N * 128;          // N*128 floats region
  int* csr = (int*)(B + (size_t)N * 128);  // E ints
  int* deg = csr + E;                      // N
  int* offs = deg + N;                     // N
  float* dinv = (float*)(offs + N);        // N
  int* cnt = (int*)A;                      // M (alias A)
  int* pos = cnt + M;                      // M (alias A)
  int* bsum = pos + M;                     // <=1024 (alias A)
  int2* pairs = (int2*)B;                  // E pairs (alias B)
  unsigned short* T1 = (unsigned short*)A;  // (N+1) x 128 bf16 (alias A)
  unsigned short* T2 = (unsigned short*)A;  // (N+1) x 64 bf16 (alias A)

  kA_count<<<NBLK, 256, 0, stream>>>(dst, E, NB, NBLK, cnt);
  k_scanA<<<NSB, 1024, 0, stream>>>(cnt, M, pos, bsum);
  k_scanB<<<1, 1024, 0, stream>>>(bsum, NSB);
  kC_scatter<<<NBLK, 256, 0, stream>>>(src, dst, E, NB, NBLK, pos, bsum, pairs);
  kD_build<<<NB, 256, 0, stream>>>(pairs, pos, bsum, N, E, NB, NBLK,
                                   csr, deg, offs, dinv);

  dim3 g1((N + 63) / 64, 2);  // 782 blocks cover rows 0..50047 >= N (zero row)
  k_gemm_bf<<<g1, 256, 0, stream>>>(x, W1, dinv, T1, N, 128, 128, N + 1);
  k_agg128_bf<<<(N + 3) / 4, 256, 0, stream>>>((const unsigned*)T1, csr, offs, deg,
                                               dinv, b1, B, N);
  dim3 g2((N + 63) / 64, 1);
  k_gemm_bf<<<g2, 256, 0, stream>>>(B, W2, dinv, T2, N, 128, 64, N + 1);
  k_agg64_bf<<<(N + 3) / 4, 256, 0, stream>>>((const unsigned*)T2, csr, offs, deg,
                                              dinv, b2, out, N);
}

// Round 5
// 204.809 us; speedup vs baseline: 2.7140x; 1.0012x over previous
//
#include <hip/hip_runtime.h>
#include <math.h>

// ---------------------------------------------------------------------------
// 2-layer GCN: out = ReLU(N(x@W1)+b1) -> N(h@W2)+b2, N(.) = D^-1/2 (A+I) D^-1/2
// dinv[src] folded into GEMM epilogue, dinv[dst] into agg epilogue.
// GEMMs: bf16 MFMA (16x16x32), 3-term split precision (hi*hi + lo*hi + hi*lo),
// fp32 accumulation -> error stays at fp32 level; table written bf16.
// Gather tables bf16 (half the 64B lines per edge); fp32 accumulation in agg.
// CSR via two-level bucket partition; pairs packed (src<<6)|dstlo in 32 bits.
// ---------------------------------------------------------------------------

#define CH 8192        // edges per partition block
#define BSH 6          // bucket shift: 64 nodes per bucket
#define NBMAX 1024     // LDS histogram capacity (buckets <= 1024)

typedef __attribute__((ext_vector_type(8))) short short8;
typedef __attribute__((ext_vector_type(4))) float f32x4;

static __device__ __forceinline__ float bflo(unsigned u) { return __uint_as_float(u << 16); }
static __device__ __forceinline__ float bfhi(unsigned u) { return __uint_as_float(u & 0xffff0000u); }
static __device__ __forceinline__ unsigned short f2bf(float f) {
  unsigned u = __float_as_uint(f);
  return (unsigned short)((u + 0x7fffu + ((u >> 16) & 1u)) >> 16);  // RNE
}
static __device__ __forceinline__ unsigned packbf(float a, float b) {
  return (unsigned)f2bf(a) | ((unsigned)f2bf(b) << 16);
}
static __device__ __forceinline__ void accum(float4& a, uint2 v) {
  a.x += bflo(v.x); a.y += bfhi(v.x); a.z += bflo(v.y); a.w += bfhi(v.y);
}
static __device__ __forceinline__ void split_bf(float x, unsigned short& h, unsigned short& l) {
  h = f2bf(x);
  float hf = __uint_as_float((unsigned)h << 16);
  l = f2bf(x - hf);
}

// ---------------- CSR build ----------------

__global__ __launch_bounds__(256) void kA_count(const int* __restrict__ dst, int E,
                                                int NB, int NBLK,
                                                int* __restrict__ cnt) {
  __shared__ int h[NBMAX];
  int t = threadIdx.x;
  int blk = blockIdx.x;
  for (int i = t; i < NB; i += 256) h[i] = 0;
  __syncthreads();
  int e0 = blk * CH;
  int e1 = min(E, e0 + CH);
  for (int e = e0 + t; e < e1; e += 256) atomicAdd(&h[dst[e] >> BSH], 1);
  __syncthreads();
  for (int i = t; i < NB; i += 256) cnt[i * NBLK + blk] = h[i];
}

__global__ __launch_bounds__(1024) void k_scanA(const int* __restrict__ in, int M,
                                                int* __restrict__ out,
                                                int* __restrict__ bsum) {
  __shared__ int sd[1024];
  int tid = threadIdx.x;
  int i = blockIdx.x * 1024 + tid;
  int v = (i < M) ? in[i] : 0;
  sd[tid] = v;
  __syncthreads();
  for (int off = 1; off < 1024; off <<= 1) {
    int t = (tid >= off) ? sd[tid - off] : 0;
    __syncthreads();
    sd[tid] += t;
    __syncthreads();
  }
  if (i < M) out[i] = sd[tid] - v;  // block-local exclusive
  if (tid == 1023) bsum[blockIdx.x] = sd[1023];  // raw block totals
}

// In-block exclusive scan of bsum (<=256 entries) into ex[]. 256 threads.
static __device__ __forceinline__ void scan_bsum_lds(const int* __restrict__ bsum,
                                                     int nsb, int t,
                                                     int* ex, int* sd) {
  int v = (t < nsb) ? bsum[t] : 0;
  ex[t] = v;
  sd[t] = v;
  __syncthreads();
  for (int off = 1; off < 256; off <<= 1) {
    int u = (t >= off) ? sd[t - off] : 0;
    __syncthreads();
    sd[t] += u;
    __syncthreads();
  }
  ex[t] = sd[t] - ex[t];  // exclusive
  __syncthreads();
}

__global__ __launch_bounds__(256) void kC_scatter(const int* __restrict__ src,
                                                  const int* __restrict__ dst, int E,
                                                  int NB, int NBLK, int NSB,
                                                  const int* __restrict__ pos,
                                                  const int* __restrict__ bsum,
                                                  int* __restrict__ ppack) {
  __shared__ int lcur[NBMAX];
  __shared__ int ex[256];
  __shared__ int sd[256];
  int t = threadIdx.x;
  int blk = blockIdx.x;
  scan_bsum_lds(bsum, NSB, t, ex, sd);
  for (int i = t; i < NB; i += 256) {
    int f = i * NBLK + blk;
    lcur[i] = pos[f] + ex[f >> 10];
  }
  __syncthreads();
  int e0 = blk * CH;
  int e1 = min(E, e0 + CH);
  for (int e = e0 + t; e < e1; e += 256) {
    int d = dst[e];
    int p = atomicAdd(&lcur[d >> BSH], 1);
    ppack[p] = (src[e] << BSH) | (d & ((1 << BSH) - 1));
  }
}

__global__ __launch_bounds__(256) void kD_build(const int* __restrict__ ppack,
                                                const int* __restrict__ pos,
                                                const int* __restrict__ bsum,
                                                int N, int E, int NB, int NBLK, int NSB,
                                                int* __restrict__ csr,
                                                int* __restrict__ deg,
                                                int* __restrict__ offs,
                                                float* __restrict__ dinv) {
  __shared__ int ex[256];
  __shared__ int sd[256];
  __shared__ int ldeg[64];
  __shared__ int lsc[64];
  __shared__ int lcur[64];
  int t = threadIdx.x;
  int q = blockIdx.x;
  scan_bsum_lds(bsum, NSB, t, ex, sd);
  int node_lo = q << BSH;
  int f0 = q * NBLK;
  int base = pos[f0] + ex[f0 >> 10];
  int end;
  if (q == NB - 1) end = E;
  else {
    int f1 = (q + 1) * NBLK;
    end = pos[f1] + ex[f1 >> 10];
  }
  if (t < 64) ldeg[t] = 0;
  __syncthreads();
  for (int e = base + t; e < end; e += 256)
    atomicAdd(&ldeg[ppack[e] & 63], 1);
  __syncthreads();
  int v = (t < 64) ? ldeg[t] : 0;
  if (t < 64) lsc[t] = v;
  __syncthreads();
  for (int off = 1; off < 64; off <<= 1) {
    int tmp = (t < 64 && t >= off) ? lsc[t - off] : 0;
    __syncthreads();
    if (t < 64) lsc[t] += tmp;
    __syncthreads();
  }
  if (t < 64) {
    int exn = lsc[t] - v;
    lcur[t] = exn;
    int g = node_lo + t;
    if (g < N) {
      deg[g] = v;
      offs[g] = base + exn;
      dinv[g] = rsqrtf((float)(v + 1));  // +1 self loop
    }
  }
  __syncthreads();
  for (int e = base + t; e < end; e += 256) {
    int pk = ppack[e];
    int p = atomicAdd(&lcur[pk & 63], 1);
    csr[base + p] = pk >> BSH;
  }
}

// ---------------- MFMA GEMM: T[r][c] = bf16( (X[r]@W)[c] * dinv[r] ) --------
// BM=32 rows/block, BN=64 cols/block, K=128 fully LDS-resident.
// Split precision: acc += Xh*Wh + Xl*Wh + Xh*Wl (fp32 MFMA accum).
// Row Mreal (dummy) written as zeros via dn=0.
__global__ __launch_bounds__(256) void k_gemm_mfma(
    const float* __restrict__ X, const float* __restrict__ W,
    const float* __restrict__ dinv, unsigned short* __restrict__ T,
    int Mreal, int Mpad, int NC) {
  // LDS: Xh[32][136], Xl[32][136], Wh[64][136], Wl[64][136] (shorts)
  __shared__ short lds[4352 * 2 + 8704 * 2];
  short* Xh = lds;
  short* Xl = lds + 4352;
  short* Wh = lds + 8704;
  short* Wl = lds + 8704 + 8704;
  const int t = threadIdx.x;
  const int bm = blockIdx.x * 32;
  const int bn = blockIdx.y * 64;

  // stage X rows [bm..bm+32) x K=128, split hi/lo
  #pragma unroll
  for (int i = 0; i < 4; ++i) {
    int slot = t + i * 256;       // 1024 float4 slots
    int row = slot >> 5;
    int q = slot & 31;
    int rr = bm + row;
    if (rr >= Mreal) rr = Mreal - 1;
    float4 v = *(const float4*)(X + (size_t)rr * 128 + q * 4);
    unsigned short h0, l0, h1, l1, h2, l2, h3, l3;
    split_bf(v.x, h0, l0); split_bf(v.y, h1, l1);
    split_bf(v.z, h2, l2); split_bf(v.w, h3, l3);
    int idx = row * 136 + q * 4;
    *(uint2*)&Xh[idx] = make_uint2((unsigned)h0 | ((unsigned)h1 << 16),
                                   (unsigned)h2 | ((unsigned)h3 << 16));
    *(uint2*)&Xl[idx] = make_uint2((unsigned)l0 | ((unsigned)l1 << 16),
                                   (unsigned)l2 | ((unsigned)l3 << 16));
  }
  // stage W cols [bn..bn+64) x K=128 transposed to [n][k], split hi/lo
  #pragma unroll
  for (int i = 0; i < 8; ++i) {
    int slot = t + i * 256;       // 2048 float4 slots
    int k = slot >> 4;
    int q = slot & 15;
    float4 v = *(const float4*)(W + (size_t)k * NC + bn + q * 4);
    unsigned short h, l;
    split_bf(v.x, h, l); Wh[(q * 4 + 0) * 136 + k] = h; Wl[(q * 4 + 0) * 136 + k] = l;
    split_bf(v.y, h, l); Wh[(q * 4 + 1) * 136 + k] = h; Wl[(q * 4 + 1) * 136 + k] = l;
    split_bf(v.z, h, l); Wh[(q * 4 + 2) * 136 + k] = h; Wl[(q * 4 + 2) * 136 + k] = l;
    split_bf(v.w, h, l); Wh[(q * 4 + 3) * 136 + k] = h; Wl[(q * 4 + 3) * 136 + k] = l;
  }
  __syncthreads();

  const int lane = t & 63;
  const int wid = t >> 6;
  const int wm = wid >> 1;   // 0..1: m-range of 16
  const int wn = wid & 1;    // 0..1: n-range of 32
  const int lm = lane & 15;
  const int kg = lane >> 4;  // k-group 0..3
  f32x4 acc[2] = {{0.f, 0.f, 0.f, 0.f}, {0.f, 0.f, 0.f, 0.f}};
  #pragma unroll
  for (int ks = 0; ks < 4; ++ks) {
    int kof = ks * 32 + kg * 8;
    short8 ah = *(const short8*)&Xh[(wm * 16 + lm) * 136 + kof];
    short8 al = *(const short8*)&Xl[(wm * 16 + lm) * 136 + kof];
    #pragma unroll
    for (int nt = 0; nt < 2; ++nt) {
      int nrow = (wn * 32 + nt * 16 + lm) * 136 + kof;
      short8 bh = *(const short8*)&Wh[nrow];
      short8 bl = *(const short8*)&Wl[nrow];
      acc[nt] = __builtin_amdgcn_mfma_f32_16x16x32_bf16(ah, bh, acc[nt], 0, 0, 0);
      acc[nt] = __builtin_amdgcn_mfma_f32_16x16x32_bf16(al, bh, acc[nt], 0, 0, 0);
      acc[nt] = __builtin_amdgcn_mfma_f32_16x16x32_bf16(ah, bl, acc[nt], 0, 0, 0);
    }
  }
  // epilogue: repack via LDS (reuse Xh/Xl region), coalesced bf16 row writes
  __syncthreads();
  float* rep = (float*)lds;  // [32][68]
  #pragma unroll
  for (int nt = 0; nt < 2; ++nt)
    #pragma unroll
    for (int i = 0; i < 4; ++i)
      rep[(wm * 16 + kg * 4 + i) * 68 + wn * 32 + nt * 16 + lm] = acc[nt][i];
  __syncthreads();
  #pragma unroll
  for (int it = 0; it < 2; ++it) {
    int slot = t + it * 256;   // 512 uint2 slots: 32 rows x 16
    int lrow = slot >> 4;
    int q = slot & 15;
    int gr = bm + lrow;
    if (gr < Mpad) {
      float dn = (gr < Mreal) ? dinv[gr] : 0.f;
      const float* rp = rep + lrow * 68 + q * 4;
      uint2 o = make_uint2(packbf(rp[0] * dn, rp[1] * dn),
                           packbf(rp[2] * dn, rp[3] * dn));
      *(uint2*)(T + (size_t)gr * NC + bn + q * 4) = o;
    }
  }
}

// ---------------- Aggregation (unchanged from R3) ----------------

__global__ __launch_bounds__(256) void k_agg128_bf(
    const unsigned* __restrict__ T, const int* __restrict__ csr,
    const int* __restrict__ offs, const int* __restrict__ deg,
    const float* __restrict__ dinv, const float* __restrict__ bias,
    float* __restrict__ Bout, int N) {
  int wave = threadIdx.x >> 6;
  int lane = threadIdx.x & 63;
  int node = blockIdx.x * 4 + wave;
  if (node >= N) return;
  int start = offs[node];
  int cnt = deg[node];
  int half = lane >> 5;
  int fl = lane & 31;
  const uint2* Tq = (const uint2*)T;  // row = 32 uint2
  float4 a0 = {0, 0, 0, 0}, a1 = {0, 0, 0, 0}, a2 = {0, 0, 0, 0}, a3 = {0, 0, 0, 0};
  float4 a4 = {0, 0, 0, 0}, a5 = {0, 0, 0, 0}, a6 = {0, 0, 0, 0}, a7 = {0, 0, 0, 0};
  {
    int s = half ? N : node;  // self loop / zero row
    accum(a0, Tq[(size_t)s * 32 + fl]);
  }
  int j = 0;
  for (; j + 16 <= cnt; j += 16) {
    int b = start + j + half;
    int s0 = csr[b + 0],  s1 = csr[b + 2],  s2 = csr[b + 4],  s3 = csr[b + 6];
    int s4 = csr[b + 8],  s5 = csr[b + 10], s6 = csr[b + 12], s7 = csr[b + 14];
    uint2 v0 = Tq[(size_t)s0 * 32 + fl];
    uint2 v1 = Tq[(size_t)s1 * 32 + fl];
    uint2 v2 = Tq[(size_t)s2 * 32 + fl];
    uint2 v3 = Tq[(size_t)s3 * 32 + fl];
    uint2 v4 = Tq[(size_t)s4 * 32 + fl];
    uint2 v5 = Tq[(size_t)s5 * 32 + fl];
    uint2 v6 = Tq[(size_t)s6 * 32 + fl];
    uint2 v7 = Tq[(size_t)s7 * 32 + fl];
    accum(a0, v0); accum(a1, v1); accum(a2, v2); accum(a3, v3);
    accum(a4, v4); accum(a5, v5); accum(a6, v6); accum(a7, v7);
  }
  for (; j < cnt; j += 2) {
    int idx = j + half;
    int s = (idx < cnt) ? csr[start + idx] : N;
    accum(a0, Tq[(size_t)s * 32 + fl]);
  }
  a0.x += a1.x; a0.y += a1.y; a0.z += a1.z; a0.w += a1.w;
  a2.x += a3.x; a2.y += a3.y; a2.z += a3.z; a2.w += a3.w;
  a4.x += a5.x; a4.y += a5.y; a4.z += a5.z; a4.w += a5.w;
  a6.x += a7.x; a6.y += a7.y; a6.z += a7.z; a6.w += a7.w;
  a0.x += a2.x; a0.y += a2.y; a0.z += a2.z; a0.w += a2.w;
  a4.x += a6.x; a4.y += a6.y; a4.z += a6.z; a4.w += a6.w;
  a0.x += a4.x; a0.y += a4.y; a0.z += a4.z; a0.w += a4.w;
  a0.x += __shfl_xor(a0.x, 32, 64);
  a0.y += __shfl_xor(a0.y, 32, 64);
  a0.z += __shfl_xor(a0.z, 32, 64);
  a0.w += __shfl_xor(a0.w, 32, 64);
  if (half == 0) {
    float dn = dinv[node];
    float4 bb = ((const float4*)bias)[fl];
    float4 o;
    o.x = fmaxf(fmaf(a0.x, dn, bb.x), 0.f);
    o.y = fmaxf(fmaf(a0.y, dn, bb.y), 0.f);
    o.z = fmaxf(fmaf(a0.z, dn, bb.z), 0.f);
    o.w = fmaxf(fmaf(a0.w, dn, bb.w), 0.f);
    ((float4*)Bout)[(size_t)node * 32 + fl] = o;
  }
}

__global__ __launch_bounds__(256) void k_agg64_bf(
    const unsigned* __restrict__ T, const int* __restrict__ csr,
    const int* __restrict__ offs, const int* __restrict__ deg,
    const float* __restrict__ dinv, const float* __restrict__ bias,
    float* __restrict__ Out, int N) {
  int wave = threadIdx.x >> 6;
  int lane = threadIdx.x & 63;
  int node = blockIdx.x * 4 + wave;
  if (node >= N) return;
  int start = offs[node];
  int cnt = deg[node];
  int g = lane >> 4;
  int fl = lane & 15;
  const uint2* Tq = (const uint2*)T;  // row = 16 uint2
  float4 a0 = {0, 0, 0, 0}, a1 = {0, 0, 0, 0}, a2 = {0, 0, 0, 0}, a3 = {0, 0, 0, 0};
  {
    int s = (g == 0) ? node : N;
    accum(a0, Tq[(size_t)s * 16 + fl]);
  }
  int j = 0;
  for (; j + 16 <= cnt; j += 16) {
    int b = start + j + g;
    int s0 = csr[b + 0], s1 = csr[b + 4], s2 = csr[b + 8], s3 = csr[b + 12];
    uint2 v0 = Tq[(size_t)s0 * 16 + fl];
    uint2 v1 = Tq[(size_t)s1 * 16 + fl];
    uint2 v2 = Tq[(size_t)s2 * 16 + fl];
    uint2 v3 = Tq[(size_t)s3 * 16 + fl];
    accum(a0, v0); accum(a1, v1); accum(a2, v2); accum(a3, v3);
  }
  for (; j < cnt; j += 4) {
    int idx = j + g;
    int s = (idx < cnt) ? csr[start + idx] : N;
    accum(a0, Tq[(size_t)s * 16 + fl]);
  }
  a0.x += a1.x; a0.y += a1.y; a0.z += a1.z; a0.w += a1.w;
  a2.x += a3.x; a2.y += a3.y; a2.z += a3.z; a2.w += a3.w;
  a0.x += a2.x; a0.y += a2.y; a0.z += a2.z; a0.w += a2.w;
  a0.x += __shfl_xor(a0.x, 32, 64);
  a0.y += __shfl_xor(a0.y, 32, 64);
  a0.z += __shfl_xor(a0.z, 32, 64);
  a0.w += __shfl_xor(a0.w, 32, 64);
  a0.x += __shfl_xor(a0.x, 16, 64);
  a0.y += __shfl_xor(a0.y, 16, 64);
  a0.z += __shfl_xor(a0.z, 16, 64);
  a0.w += __shfl_xor(a0.w, 16, 64);
  if (lane < 16) {
    float dn = dinv[node];
    float4 bb = ((const float4*)bias)[fl];
    float4 o;
    o.x = fmaf(a0.x, dn, bb.x);
    o.y = fmaf(a0.y, dn, bb.y);
    o.z = fmaf(a0.z, dn, bb.z);
    o.w = fmaf(a0.w, dn, bb.w);
    ((float4*)Out)[(size_t)node * 16 + fl] = o;
  }
}

extern "C" void kernel_launch(void* const* d_in, const int* in_sizes, int n_in,
                              void* d_out, int out_size, void* d_ws, size_t ws_size,
                              hipStream_t stream) {
  const float* x = (const float*)d_in[0];
  const int* ei = (const int*)d_in[1];
  const float* W1 = (const float*)d_in[2];
  const float* b1 = (const float*)d_in[3];
  const float* W2 = (const float*)d_in[4];
  const float* b2 = (const float*)d_in[5];
  float* out = (float*)d_out;

  const int N = in_sizes[0] / 128;  // 50000
  const int E = in_sizes[1] / 2;    // 1600000
  const int* src = ei;
  const int* dst = ei + E;

  const int NB = (N + (1 << BSH) - 1) >> BSH;  // buckets (782)
  const int NBLK = (E + CH - 1) / CH;          // partition blocks (196)
  const int M = NB * NBLK;                     // count-table entries (153272)
  const int NSB = (M + 1023) / 1024;           // scan blocks (150, <=256)

  // workspace layout (aliased; tables live in A region, packed pairs in B)
  float* A = (float*)d_ws;                 // N*128 floats region
  float* B = A + (size_t)N * 128;          // N*128 floats region
  int* csr = (int*)(B + (size_t)N * 128);  // E ints
  int* deg = csr + E;                      // N
  int* offs = deg + N;                     // N
  float* dinv = (float*)(offs + N);        // N
  int* cnt = (int*)A;                      // M (alias A)
  int* pos = cnt + M;                      // M (alias A)
  int* bsum = pos + M;                     // <=256 (alias A)
  int* ppack = (int*)B;                    // E packed pairs (alias B)
  unsigned short* T1 = (unsigned short*)A;  // (N+1) x 128 bf16 (alias A)
  unsigned short* T2 = (unsigned short*)A;  // (N+1) x 64 bf16 (alias A)

  kA_count<<<NBLK, 256, 0, stream>>>(dst, E, NB, NBLK, cnt);
  k_scanA<<<NSB, 1024, 0, stream>>>(cnt, M, pos, bsum);
  kC_scatter<<<NBLK, 256, 0, stream>>>(src, dst, E, NB, NBLK, NSB, pos, bsum, ppack);
  kD_build<<<NB, 256, 0, stream>>>(ppack, pos, bsum, N, E, NB, NBLK, NSB,
                                   csr, deg, offs, dinv);

  const int MT = (N + 1 + 31) / 32;  // 1563 m-blocks (covers dummy row N)
  dim3 g1(MT, 2);
  k_gemm_mfma<<<g1, 256, 0, stream>>>(x, W1, dinv, T1, N, N + 1, 128);
  k_agg128_bf<<<(N + 3) / 4, 256, 0, stream>>>((const unsigned*)T1, csr, offs, deg,
                                               dinv, b1, B, N);
  dim3 g2(MT, 1);
  k_gemm_mfma<<<g2, 256, 0, stream>>>(B, W2, dinv, T2, N, N + 1, 64);
  k_agg64_bf<<<(N + 3) / 4, 256, 0, stream>>>((const unsigned*)T2, csr, offs, deg,
                                              dinv, b2, out, N);
}

// Round 6
// 195.917 us; speedup vs baseline: 2.8372x; 1.0454x over previous
//
#include <hip/hip_runtime.h>
#include <math.h>

// ---------------------------------------------------------------------------
// 2-layer GCN: out = ReLU(N(x@W1)+b1) -> N(h@W2)+b2, N(.) = D^-1/2 (A+I) D^-1/2
// dinv[src] folded into GEMM epilogue, dinv[dst] into agg epilogue.
// GEMMs: bf16 MFMA (16x16x32), 3-term split precision, fp32 accumulation.
// Gather tables bf16; fp32 accumulation in agg. Agg kernels software-pipeline
// the csr-index stream (prefetch next batch before gathers) and predicate the
// tail against the dummy zero row N (csr padded by 64 ints -> safe raw reads).
// CSR via two-level bucket partition; pairs packed (src<<6)|dstlo in 32 bits.
// ---------------------------------------------------------------------------

#define CH 8192        // edges per partition block
#define BSH 6          // bucket shift: 64 nodes per bucket
#define NBMAX 1024     // LDS histogram capacity (buckets <= 1024)

typedef __attribute__((ext_vector_type(8))) short short8;
typedef __attribute__((ext_vector_type(4))) float f32x4;

static __device__ __forceinline__ float bflo(unsigned u) { return __uint_as_float(u << 16); }
static __device__ __forceinline__ float bfhi(unsigned u) { return __uint_as_float(u & 0xffff0000u); }
static __device__ __forceinline__ unsigned short f2bf(float f) {
  unsigned u = __float_as_uint(f);
  return (unsigned short)((u + 0x7fffu + ((u >> 16) & 1u)) >> 16);  // RNE
}
static __device__ __forceinline__ unsigned packbf(float a, float b) {
  return (unsigned)f2bf(a) | ((unsigned)f2bf(b) << 16);
}
static __device__ __forceinline__ void accum(float4& a, uint2 v) {
  a.x += bflo(v.x); a.y += bfhi(v.x); a.z += bflo(v.y); a.w += bfhi(v.y);
}
static __device__ __forceinline__ void split_bf(float x, unsigned short& h, unsigned short& l) {
  h = f2bf(x);
  float hf = __uint_as_float((unsigned)h << 16);
  l = f2bf(x - hf);
}

// ---------------- CSR build ----------------

__global__ __launch_bounds__(256) void kA_count(const int* __restrict__ dst, int E,
                                                int NB, int NBLK,
                                                int* __restrict__ cnt) {
  __shared__ int h[NBMAX];
  int t = threadIdx.x;
  int blk = blockIdx.x;
  for (int i = t; i < NB; i += 256) h[i] = 0;
  __syncthreads();
  int e0 = blk * CH;
  int e1 = min(E, e0 + CH);
  for (int e = e0 + t; e < e1; e += 256) atomicAdd(&h[dst[e] >> BSH], 1);
  __syncthreads();
  for (int i = t; i < NB; i += 256) cnt[i * NBLK + blk] = h[i];
}

__global__ __launch_bounds__(1024) void k_scanA(const int* __restrict__ in, int M,
                                                int* __restrict__ out,
                                                int* __restrict__ bsum) {
  __shared__ int sd[1024];
  int tid = threadIdx.x;
  int i = blockIdx.x * 1024 + tid;
  int v = (i < M) ? in[i] : 0;
  sd[tid] = v;
  __syncthreads();
  for (int off = 1; off < 1024; off <<= 1) {
    int t = (tid >= off) ? sd[tid - off] : 0;
    __syncthreads();
    sd[tid] += t;
    __syncthreads();
  }
  if (i < M) out[i] = sd[tid] - v;  // block-local exclusive
  if (tid == 1023) bsum[blockIdx.x] = sd[1023];  // raw block totals
}

// In-block exclusive scan of bsum (<=256 entries) into ex[]. 256 threads.
static __device__ __forceinline__ void scan_bsum_lds(const int* __restrict__ bsum,
                                                     int nsb, int t,
                                                     int* ex, int* sd) {
  int v = (t < nsb) ? bsum[t] : 0;
  ex[t] = v;
  sd[t] = v;
  __syncthreads();
  for (int off = 1; off < 256; off <<= 1) {
    int u = (t >= off) ? sd[t - off] : 0;
    __syncthreads();
    sd[t] += u;
    __syncthreads();
  }
  ex[t] = sd[t] - ex[t];  // exclusive
  __syncthreads();
}

__global__ __launch_bounds__(256) void kC_scatter(const int* __restrict__ src,
                                                  const int* __restrict__ dst, int E,
                                                  int NB, int NBLK, int NSB,
                                                  const int* __restrict__ pos,
                                                  const int* __restrict__ bsum,
                                                  int* __restrict__ ppack) {
  __shared__ int lcur[NBMAX];
  __shared__ int ex[256];
  __shared__ int sd[256];
  int t = threadIdx.x;
  int blk = blockIdx.x;
  scan_bsum_lds(bsum, NSB, t, ex, sd);
  for (int i = t; i < NB; i += 256) {
    int f = i * NBLK + blk;
    lcur[i] = pos[f] + ex[f >> 10];
  }
  __syncthreads();
  int e0 = blk * CH;
  int e1 = min(E, e0 + CH);
  for (int e = e0 + t; e < e1; e += 256) {
    int d = dst[e];
    int p = atomicAdd(&lcur[d >> BSH], 1);
    ppack[p] = (src[e] << BSH) | (d & ((1 << BSH) - 1));
  }
}

__global__ __launch_bounds__(256) void kD_build(const int* __restrict__ ppack,
                                                const int* __restrict__ pos,
                                                const int* __restrict__ bsum,
                                                int N, int E, int NB, int NBLK, int NSB,
                                                int* __restrict__ csr,
                                                int* __restrict__ deg,
                                                int* __restrict__ offs,
                                                float* __restrict__ dinv) {
  __shared__ int ex[256];
  __shared__ int sd[256];
  __shared__ int ldeg[64];
  __shared__ int lsc[64];
  __shared__ int lcur[64];
  int t = threadIdx.x;
  int q = blockIdx.x;
  scan_bsum_lds(bsum, NSB, t, ex, sd);
  int node_lo = q << BSH;
  int f0 = q * NBLK;
  int base = pos[f0] + ex[f0 >> 10];
  int end;
  if (q == NB - 1) end = E;
  else {
    int f1 = (q + 1) * NBLK;
    end = pos[f1] + ex[f1 >> 10];
  }
  if (t < 64) ldeg[t] = 0;
  __syncthreads();
  for (int e = base + t; e < end; e += 256)
    atomicAdd(&ldeg[ppack[e] & 63], 1);
  __syncthreads();
  int v = (t < 64) ? ldeg[t] : 0;
  if (t < 64) lsc[t] = v;
  __syncthreads();
  for (int off = 1; off < 64; off <<= 1) {
    int tmp = (t < 64 && t >= off) ? lsc[t - off] : 0;
    __syncthreads();
    if (t < 64) lsc[t] += tmp;
    __syncthreads();
  }
  if (t < 64) {
    int exn = lsc[t] - v;
    lcur[t] = exn;
    int g = node_lo + t;
    if (g < N) {
      deg[g] = v;
      offs[g] = base + exn;
      dinv[g] = rsqrtf((float)(v + 1));  // +1 self loop
    }
  }
  __syncthreads();
  for (int e = base + t; e < end; e += 256) {
    int pk = ppack[e];
    int p = atomicAdd(&lcur[pk & 63], 1);
    csr[base + p] = pk >> BSH;
  }
}

// ---------------- MFMA GEMM: T[r][c] = bf16( (X[r]@W)[c] * dinv[r] ) --------
__global__ __launch_bounds__(256) void k_gemm_mfma(
    const float* __restrict__ X, const float* __restrict__ W,
    const float* __restrict__ dinv, unsigned short* __restrict__ T,
    int Mreal, int Mpad, int NC) {
  __shared__ short lds[4352 * 2 + 8704 * 2];
  short* Xh = lds;
  short* Xl = lds + 4352;
  short* Wh = lds + 8704;
  short* Wl = lds + 8704 + 8704;
  const int t = threadIdx.x;
  const int bm = blockIdx.x * 32;
  const int bn = blockIdx.y * 64;

  #pragma unroll
  for (int i = 0; i < 4; ++i) {
    int slot = t + i * 256;
    int row = slot >> 5;
    int q = slot & 31;
    int rr = bm + row;
    if (rr >= Mreal) rr = Mreal - 1;
    float4 v = *(const float4*)(X + (size_t)rr * 128 + q * 4);
    unsigned short h0, l0, h1, l1, h2, l2, h3, l3;
    split_bf(v.x, h0, l0); split_bf(v.y, h1, l1);
    split_bf(v.z, h2, l2); split_bf(v.w, h3, l3);
    int idx = row * 136 + q * 4;
    *(uint2*)&Xh[idx] = make_uint2((unsigned)h0 | ((unsigned)h1 << 16),
                                   (unsigned)h2 | ((unsigned)h3 << 16));
    *(uint2*)&Xl[idx] = make_uint2((unsigned)l0 | ((unsigned)l1 << 16),
                                   (unsigned)l2 | ((unsigned)l3 << 16));
  }
  #pragma unroll
  for (int i = 0; i < 8; ++i) {
    int slot = t + i * 256;
    int k = slot >> 4;
    int q = slot & 15;
    float4 v = *(const float4*)(W + (size_t)k * NC + bn + q * 4);
    unsigned short h, l;
    split_bf(v.x, h, l); Wh[(q * 4 + 0) * 136 + k] = h; Wl[(q * 4 + 0) * 136 + k] = l;
    split_bf(v.y, h, l); Wh[(q * 4 + 1) * 136 + k] = h; Wl[(q * 4 + 1) * 136 + k] = l;
    split_bf(v.z, h, l); Wh[(q * 4 + 2) * 136 + k] = h; Wl[(q * 4 + 2) * 136 + k] = l;
    split_bf(v.w, h, l); Wh[(q * 4 + 3) * 136 + k] = h; Wl[(q * 4 + 3) * 136 + k] = l;
  }
  __syncthreads();

  const int lane = t & 63;
  const int wid = t >> 6;
  const int wm = wid >> 1;
  const int wn = wid & 1;
  const int lm = lane & 15;
  const int kg = lane >> 4;
  f32x4 acc[2] = {{0.f, 0.f, 0.f, 0.f}, {0.f, 0.f, 0.f, 0.f}};
  #pragma unroll
  for (int ks = 0; ks < 4; ++ks) {
    int kof = ks * 32 + kg * 8;
    short8 ah = *(const short8*)&Xh[(wm * 16 + lm) * 136 + kof];
    short8 al = *(const short8*)&Xl[(wm * 16 + lm) * 136 + kof];
    #pragma unroll
    for (int nt = 0; nt < 2; ++nt) {
      int nrow = (wn * 32 + nt * 16 + lm) * 136 + kof;
      short8 bh = *(const short8*)&Wh[nrow];
      short8 bl = *(const short8*)&Wl[nrow];
      acc[nt] = __builtin_amdgcn_mfma_f32_16x16x32_bf16(ah, bh, acc[nt], 0, 0, 0);
      acc[nt] = __builtin_amdgcn_mfma_f32_16x16x32_bf16(al, bh, acc[nt], 0, 0, 0);
      acc[nt] = __builtin_amdgcn_mfma_f32_16x16x32_bf16(ah, bl, acc[nt], 0, 0, 0);
    }
  }
  __syncthreads();
  float* rep = (float*)lds;  // [32][68]
  #pragma unroll
  for (int nt = 0; nt < 2; ++nt)
    #pragma unroll
    for (int i = 0; i < 4; ++i)
      rep[(wm * 16 + kg * 4 + i) * 68 + wn * 32 + nt * 16 + lm] = acc[nt][i];
  __syncthreads();
  #pragma unroll
  for (int it = 0; it < 2; ++it) {
    int slot = t + it * 256;
    int lrow = slot >> 4;
    int q = slot & 15;
    int gr = bm + lrow;
    if (gr < Mpad) {
      float dn = (gr < Mreal) ? dinv[gr] : 0.f;
      const float* rp = rep + lrow * 68 + q * 4;
      uint2 o = make_uint2(packbf(rp[0] * dn, rp[1] * dn),
                           packbf(rp[2] * dn, rp[3] * dn));
      *(uint2*)(T + (size_t)gr * NC + bn + q * 4) = o;
    }
  }
}

// ---------------- Aggregation: pipelined index stream + predicated tail -----

// Layer 1: 128 feats, wave/node, half-wave per edge (32 lanes x 8B).
// 16 edges/iter; next batch's csr indices prefetched before gathers.
__global__ __launch_bounds__(256) void k_agg128_bf(
    const unsigned* __restrict__ T, const int* __restrict__ csr,
    const int* __restrict__ offs, const int* __restrict__ deg,
    const float* __restrict__ dinv, const float* __restrict__ bias,
    float* __restrict__ Bout, int N) {
  int wave = threadIdx.x >> 6;
  int lane = threadIdx.x & 63;
  int node = blockIdx.x * 4 + wave;
  if (node >= N) return;
  int start = offs[node];
  int cnt = deg[node];
  int half = lane >> 5;
  int fl = lane & 31;
  const uint2* Tq = (const uint2*)T;  // row = 32 uint2
  float4 a0 = {0, 0, 0, 0}, a1 = {0, 0, 0, 0}, a2 = {0, 0, 0, 0}, a3 = {0, 0, 0, 0};
  float4 a4 = {0, 0, 0, 0}, a5 = {0, 0, 0, 0}, a6 = {0, 0, 0, 0}, a7 = {0, 0, 0, 0};
  {
    int s = half ? N : node;  // self loop / zero row
    accum(a0, Tq[(size_t)s * 32 + fl]);
  }
  int niter = (cnt + 15) >> 4;
  int b0 = start + half;
  // raw prologue loads (csr padded by 64 ints -> always in-bounds memory)
  int r0 = csr[b0 + 0],  r1 = csr[b0 + 2],  r2 = csr[b0 + 4],  r3 = csr[b0 + 6];
  int r4 = csr[b0 + 8],  r5 = csr[b0 + 10], r6 = csr[b0 + 12], r7 = csr[b0 + 14];
  for (int it = 0; it < niter; ++it) {
    int j = it << 4;
    int bn = b0 + j + 16;
    // prefetch next batch before issuing gathers (breaks idx->gather chain)
    int n0 = csr[bn + 0],  n1 = csr[bn + 2],  n2 = csr[bn + 4],  n3 = csr[bn + 6];
    int n4 = csr[bn + 8],  n5 = csr[bn + 10], n6 = csr[bn + 12], n7 = csr[bn + 14];
    int lim = cnt - j - half;  // slot i valid iff 2*i < lim
    int s0 = (0 < lim) ? r0 : N;
    int s1 = (2 < lim) ? r1 : N;
    int s2 = (4 < lim) ? r2 : N;
    int s3 = (6 < lim) ? r3 : N;
    int s4 = (8 < lim) ? r4 : N;
    int s5 = (10 < lim) ? r5 : N;
    int s6 = (12 < lim) ? r6 : N;
    int s7 = (14 < lim) ? r7 : N;
    uint2 v0 = Tq[(size_t)s0 * 32 + fl];
    uint2 v1 = Tq[(size_t)s1 * 32 + fl];
    uint2 v2 = Tq[(size_t)s2 * 32 + fl];
    uint2 v3 = Tq[(size_t)s3 * 32 + fl];
    uint2 v4 = Tq[(size_t)s4 * 32 + fl];
    uint2 v5 = Tq[(size_t)s5 * 32 + fl];
    uint2 v6 = Tq[(size_t)s6 * 32 + fl];
    uint2 v7 = Tq[(size_t)s7 * 32 + fl];
    accum(a0, v0); accum(a1, v1); accum(a2, v2); accum(a3, v3);
    accum(a4, v4); accum(a5, v5); accum(a6, v6); accum(a7, v7);
    r0 = n0; r1 = n1; r2 = n2; r3 = n3;
    r4 = n4; r5 = n5; r6 = n6; r7 = n7;
  }
  a0.x += a1.x; a0.y += a1.y; a0.z += a1.z; a0.w += a1.w;
  a2.x += a3.x; a2.y += a3.y; a2.z += a3.z; a2.w += a3.w;
  a4.x += a5.x; a4.y += a5.y; a4.z += a5.z; a4.w += a5.w;
  a6.x += a7.x; a6.y += a7.y; a6.z += a7.z; a6.w += a7.w;
  a0.x += a2.x; a0.y += a2.y; a0.z += a2.z; a0.w += a2.w;
  a4.x += a6.x; a4.y += a6.y; a4.z += a6.z; a4.w += a6.w;
  a0.x += a4.x; a0.y += a4.y; a0.z += a4.z; a0.w += a4.w;
  a0.x += __shfl_xor(a0.x, 32, 64);
  a0.y += __shfl_xor(a0.y, 32, 64);
  a0.z += __shfl_xor(a0.z, 32, 64);
  a0.w += __shfl_xor(a0.w, 32, 64);
  if (half == 0) {
    float dn = dinv[node];
    float4 bb = ((const float4*)bias)[fl];
    float4 o;
    o.x = fmaxf(fmaf(a0.x, dn, bb.x), 0.f);
    o.y = fmaxf(fmaf(a0.y, dn, bb.y), 0.f);
    o.z = fmaxf(fmaf(a0.z, dn, bb.z), 0.f);
    o.w = fmaxf(fmaf(a0.w, dn, bb.w), 0.f);
    ((float4*)Bout)[(size_t)node * 32 + fl] = o;
  }
}

// Layer 2: 64 feats, wave/node, quarter-wave per edge (16 lanes x 8B).
// 32 edges/iter (8 slots per group), prefetched + predicated.
__global__ __launch_bounds__(256) void k_agg64_bf(
    const unsigned* __restrict__ T, const int* __restrict__ csr,
    const int* __restrict__ offs, const int* __restrict__ deg,
    const float* __restrict__ dinv, const float* __restrict__ bias,
    float* __restrict__ Out, int N) {
  int wave = threadIdx.x >> 6;
  int lane = threadIdx.x & 63;
  int node = blockIdx.x * 4 + wave;
  if (node >= N) return;
  int start = offs[node];
  int cnt = deg[node];
  int g = lane >> 4;   // edge slot group 0..3
  int fl = lane & 15;
  const uint2* Tq = (const uint2*)T;  // row = 16 uint2
  float4 a0 = {0, 0, 0, 0}, a1 = {0, 0, 0, 0}, a2 = {0, 0, 0, 0}, a3 = {0, 0, 0, 0};
  float4 a4 = {0, 0, 0, 0}, a5 = {0, 0, 0, 0}, a6 = {0, 0, 0, 0}, a7 = {0, 0, 0, 0};
  {
    int s = (g == 0) ? node : N;  // self loop
    accum(a0, Tq[(size_t)s * 16 + fl]);
  }
  int niter = (cnt + 31) >> 5;
  int b0 = start + g;
  int r0 = csr[b0 + 0],  r1 = csr[b0 + 4],  r2 = csr[b0 + 8],  r3 = csr[b0 + 12];
  int r4 = csr[b0 + 16], r5 = csr[b0 + 20], r6 = csr[b0 + 24], r7 = csr[b0 + 28];
  for (int it = 0; it < niter; ++it) {
    int j = it << 5;
    int bn = b0 + j + 32;
    int n0 = csr[bn + 0],  n1 = csr[bn + 4],  n2 = csr[bn + 8],  n3 = csr[bn + 12];
    int n4 = csr[bn + 16], n5 = csr[bn + 20], n6 = csr[bn + 24], n7 = csr[bn + 28];
    int lim = cnt - j - g;  // slot i valid iff 4*i < lim
    int s0 = (0 < lim) ? r0 : N;
    int s1 = (4 < lim) ? r1 : N;
    int s2 = (8 < lim) ? r2 : N;
    int s3 = (12 < lim) ? r3 : N;
    int s4 = (16 < lim) ? r4 : N;
    int s5 = (20 < lim) ? r5 : N;
    int s6 = (24 < lim) ? r6 : N;
    int s7 = (28 < lim) ? r7 : N;
    uint2 v0 = Tq[(size_t)s0 * 16 + fl];
    uint2 v1 = Tq[(size_t)s1 * 16 + fl];
    uint2 v2 = Tq[(size_t)s2 * 16 + fl];
    uint2 v3 = Tq[(size_t)s3 * 16 + fl];
    uint2 v4 = Tq[(size_t)s4 * 16 + fl];
    uint2 v5 = Tq[(size_t)s5 * 16 + fl];
    uint2 v6 = Tq[(size_t)s6 * 16 + fl];
    uint2 v7 = Tq[(size_t)s7 * 16 + fl];
    accum(a0, v0); accum(a1, v1); accum(a2, v2); accum(a3, v3);
    accum(a4, v4); accum(a5, v5); accum(a6, v6); accum(a7, v7);
    r0 = n0; r1 = n1; r2 = n2; r3 = n3;
    r4 = n4; r5 = n5; r6 = n6; r7 = n7;
  }
  a0.x += a1.x; a0.y += a1.y; a0.z += a1.z; a0.w += a1.w;
  a2.x += a3.x; a2.y += a3.y; a2.z += a3.z; a2.w += a3.w;
  a4.x += a5.x; a4.y += a5.y; a4.z += a5.z; a4.w += a5.w;
  a6.x += a7.x; a6.y += a7.y; a6.z += a7.z; a6.w += a7.w;
  a0.x += a2.x; a0.y += a2.y; a0.z += a2.z; a0.w += a2.w;
  a4.x += a6.x; a4.y += a6.y; a4.z += a6.z; a4.w += a6.w;
  a0.x += a4.x; a0.y += a4.y; a0.z += a4.z; a0.w += a4.w;
  a0.x += __shfl_xor(a0.x, 32, 64);
  a0.y += __shfl_xor(a0.y, 32, 64);
  a0.z += __shfl_xor(a0.z, 32, 64);
  a0.w += __shfl_xor(a0.w, 32, 64);
  a0.x += __shfl_xor(a0.x, 16, 64);
  a0.y += __shfl_xor(a0.y, 16, 64);
  a0.z += __shfl_xor(a0.z, 16, 64);
  a0.w += __shfl_xor(a0.w, 16, 64);
  if (lane < 16) {
    float dn = dinv[node];
    float4 bb = ((const float4*)bias)[fl];
    float4 o;
    o.x = fmaf(a0.x, dn, bb.x);
    o.y = fmaf(a0.y, dn, bb.y);
    o.z = fmaf(a0.z, dn, bb.z);
    o.w = fmaf(a0.w, dn, bb.w);
    ((float4*)Out)[(size_t)node * 16 + fl] = o;
  }
}

extern "C" void kernel_launch(void* const* d_in, const int* in_sizes, int n_in,
                              void* d_out, int out_size, void* d_ws, size_t ws_size,
                              hipStream_t stream) {
  const float* x = (const float*)d_in[0];
  const int* ei = (const int*)d_in[1];
  const float* W1 = (const float*)d_in[2];
  const float* b1 = (const float*)d_in[3];
  const float* W2 = (const float*)d_in[4];
  const float* b2 = (const float*)d_in[5];
  float* out = (float*)d_out;

  const int N = in_sizes[0] / 128;  // 50000
  const int E = in_sizes[1] / 2;    // 1600000
  const int* src = ei;
  const int* dst = ei + E;

  const int NB = (N + (1 << BSH) - 1) >> BSH;  // buckets (782)
  const int NBLK = (E + CH - 1) / CH;          // partition blocks (196)
  const int M = NB * NBLK;                     // count-table entries (153272)
  const int NSB = (M + 1023) / 1024;           // scan blocks (150, <=256)

  // workspace layout (aliased; tables live in A region, packed pairs in B)
  float* A = (float*)d_ws;                 // N*128 floats region
  float* B = A + (size_t)N * 128;          // N*128 floats region
  int* csr = (int*)(B + (size_t)N * 128);  // E ints (+64 pad for raw prefetch)
  int* deg = csr + E + 64;                 // N
  int* offs = deg + N;                     // N
  float* dinv = (float*)(offs + N);        // N
  int* cnt = (int*)A;                      // M (alias A)
  int* pos = cnt + M;                      // M (alias A)
  int* bsum = pos + M;                     // <=256 (alias A)
  int* ppack = (int*)B;                    // E packed pairs (alias B)
  unsigned short* T1 = (unsigned short*)A;  // (N+1) x 128 bf16 (alias A)
  unsigned short* T2 = (unsigned short*)A;  // (N+1) x 64 bf16 (alias A)

  kA_count<<<NBLK, 256, 0, stream>>>(dst, E, NB, NBLK, cnt);
  k_scanA<<<NSB, 1024, 0, stream>>>(cnt, M, pos, bsum);
  kC_scatter<<<NBLK, 256, 0, stream>>>(src, dst, E, NB, NBLK, NSB, pos, bsum, ppack);
  kD_build<<<NB, 256, 0, stream>>>(ppack, pos, bsum, N, E, NB, NBLK, NSB,
                                   csr, deg, offs, dinv);

  const int MT = (N + 1 + 31) / 32;  // m-blocks (covers dummy row N)
  dim3 g1(MT, 2);
  k_gemm_mfma<<<g1, 256, 0, stream>>>(x, W1, dinv, T1, N, N + 1, 128);
  k_agg128_bf<<<(N + 3) / 4, 256, 0, stream>>>((const unsigned*)T1, csr, offs, deg,
                                               dinv, b1, B, N);
  dim3 g2(MT, 1);
  k_gemm_mfma<<<g2, 256, 0, stream>>>(B, W2, dinv, T2, N, N + 1, 64);
  k_agg64_bf<<<(N + 3) / 4, 256, 0, stream>>>((const unsigned*)T2, csr, offs, deg,
                                              dinv, b2, out, N);
}